// Round 20
// baseline (487.652 us; speedup 1.0000x reference)
//
#include <hip/hip_runtime.h>
#include <hip/hip_bf16.h>
#include <hip/hip_fp16.h>

#define S_LEN 2048
#define BATCH 2
#define DIM 128
#define NH 8
#define HD 1024
#define QL 5
#define KKTOT 640   // DIM*QL
#define OCH 2048
#define MAXNNZ 384

typedef _Float16 hv2 __attribute__((ext_vector_type(2)));

#if defined(__has_builtin)
#  if __has_builtin(__builtin_amdgcn_fdot2)
#    define USE_FDOT2 1
#  endif
#endif
#ifndef USE_FDOT2
#  define USE_FDOT2 0
#endif

__device__ __forceinline__ hv2 u2h(unsigned u) {
    union { unsigned u; hv2 h; } c; c.u = u; return c.h;
}
__device__ __forceinline__ float dot2acc(unsigned a, unsigned b, float acc) {
#if USE_FDOT2
    return __builtin_amdgcn_fdot2(u2h(a), u2h(b), acc, false);
#else
    hv2 ha = u2h(a), hb = u2h(b);
    return acc + (float)ha[0] * (float)hb[0] + (float)ha[1] * (float)hb[1];
#endif
}

// ---------------- x (fp32) -> x16 (fp16)
__global__ void k_cvt_x(const float4* __restrict__ src, ushort4* __restrict__ dst, int n4) {
    int i = blockIdx.x * 256 + threadIdx.x;
    if (i >= n4) return;
    float4 v = src[i];
    ushort4 o;
    o.x = __half_as_ushort(__float2half(v.x));
    o.y = __half_as_ushort(__float2half(v.y));
    o.z = __half_as_ushort(__float2half(v.z));
    o.w = __half_as_ushort(__float2half(v.w));
    dst[i] = o;
}

// ---------------- w_qk (O,I,T) -> paired fp16: wtp[(p*QL+t)*OCH + o] = {w[o,2p,t], w[o,2p+1,t]}
__global__ void k_wqk_pair(const float* __restrict__ w, unsigned* __restrict__ wtp) {
    int j = blockIdx.x * 256 + threadIdx.x;   // 320*2048
    if (j >= (KKTOT / 2) * OCH) return;
    int o = j & 2047;
    int pt = j >> 11;            // p*5 + t
    int p = pt / QL, t = pt % QL;
    float a = w[(size_t)o * KKTOT + (2 * p) * QL + t];
    float b = w[(size_t)o * KKTOT + (2 * p + 1) * QL + t];
    unsigned lo = __half_as_ushort(__float2half(a));
    unsigned hi = __half_as_ushort(__float2half(b));
    wtp[j] = lo | (hi << 16);
}

// ---------------- w_v (128,1024) -> paired fp16: wvp[p*HD + c] = {wv[2p,c], wv[2p+1,c]}
__global__ void k_wv_pair(const float* __restrict__ wv, unsigned* __restrict__ wvp) {
    int j = blockIdx.x * 256 + threadIdx.x;   // 64*1024
    if (j >= (DIM / 2) * HD) return;
    int c = j & 1023;
    int p = j >> 10;
    float a = wv[(size_t)(2 * p) * HD + c];
    float b = wv[(size_t)(2 * p + 1) * HD + c];
    unsigned lo = __half_as_ushort(__float2half(a));
    unsigned hi = __half_as_ushort(__float2half(b));
    wvp[j] = lo | (hi << 16);
}

// ---------------- compact mask rows to CSR (deterministic ballot compaction)
__global__ void k_mask_csr(const float* __restrict__ mask, unsigned* __restrict__ cnt,
                           unsigned* __restrict__ idx) {
    __shared__ unsigned s_base;
    __shared__ unsigned s_wcnt[4];
    int r = blockIdx.x;
    int tid = threadIdx.x;
    int lane = tid & 63;
    int w = tid >> 6;
    if (tid == 0) s_base = 0;
    __syncthreads();
    for (int c0 = 0; c0 < S_LEN; c0 += 256) {
        int c = c0 + tid;
        bool act = mask[(size_t)r * S_LEN + c] > 0.5f;
        unsigned long long bal = __ballot(act);
        if (lane == 0) s_wcnt[w] = (unsigned)__popcll(bal);
        __syncthreads();
        unsigned off = s_base;
        for (int i = 0; i < w; i++) off += s_wcnt[i];
        off += (unsigned)__popcll(bal & ((1ull << lane) - 1ull));
        if (act && off < MAXNNZ) idx[r * MAXNNZ + off] = (unsigned)c;
        __syncthreads();
        if (tid == 0) s_base += s_wcnt[0] + s_wcnt[1] + s_wcnt[2] + s_wcnt[3];
        __syncthreads();
    }
    if (tid == 0) cnt[r] = (s_base < MAXNNZ) ? s_base : MAXNNZ;
}

// ---------------- value = x @ w_v + b_v, fp16 in / fp32 acc / fp16 out
// grid (BATCH*S/16, 4), block 256
__global__ void k_value16(const unsigned* __restrict__ x16u, const unsigned* __restrict__ wvp,
                          const float* __restrict__ bv, _Float16* __restrict__ val16) {
    __shared__ unsigned xs[16][64];   // 16 rows x 64 i-pairs
    int bs0 = blockIdx.x * 16;
    int c = blockIdx.y * 256 + threadIdx.x;
    for (int t = threadIdx.x; t < 16 * 64; t += 256)
        xs[t >> 6][t & 63] = x16u[(size_t)(bs0 + (t >> 6)) * 64 + (t & 63)];
    __syncthreads();
    float acc[16];
#pragma unroll
    for (int r = 0; r < 16; r++) acc[r] = 0.f;
    for (int p = 0; p < 64; p++) {
        unsigned w2 = wvp[(size_t)p * HD + c];
#pragma unroll
        for (int r = 0; r < 16; r++) acc[r] = dot2acc(xs[r][p], w2, acc[r]);
    }
    float b = bv[c];
#pragma unroll
    for (int r = 0; r < 16; r++)
        val16[(size_t)(bs0 + r) * HD + c] = (_Float16)(acc[r] + b);
}

// ---------------- qk conv, fp16 in / fp32 acc / fp16 out.  grid (BATCH*S/32, 8)
__global__ void k_qkconv16(const unsigned* __restrict__ x16u, const unsigned* __restrict__ wtp,
                           const float* __restrict__ bqk, _Float16* __restrict__ qk16) {
    __shared__ unsigned xs[36][64];   // 36 rows x 64 i-pairs
    int bs0 = blockIdx.x * 32;
    int b = bs0 >> 11;
    int s0 = bs0 & 2047;
    int o = blockIdx.y * 256 + threadIdx.x;
    for (int t = threadIdx.x; t < 36 * 64; t += 256) {
        int rr = t >> 6, p = t & 63;
        int s = s0 - 4 + rr;
        xs[rr][p] = (s >= 0) ? x16u[((size_t)b * S_LEN + s) * 64 + p] : 0u;
    }
    __syncthreads();
    float acc[32];
    float bias = bqk[o];
#pragma unroll
    for (int r = 0; r < 32; r++) acc[r] = bias;
    for (int p = 0; p < 64; p++) {
        unsigned xr[36];
#pragma unroll
        for (int rr = 0; rr < 36; rr++) xr[rr] = xs[rr][p];
#pragma unroll
        for (int t = 0; t < QL; t++) {
            unsigned w2 = wtp[(size_t)(p * QL + t) * OCH + o];
#pragma unroll
            for (int r = 0; r < 32; r++)
                acc[r] = dot2acc(xr[r + t], w2, acc[r]);
        }
    }
    for (int r = 0; r < 32; r++)
        qk16[((size_t)bs0 + r) * OCH + o] = (_Float16)acc[r];
}

// ---------------- sparse attention + entmax15 — ALL 8 HEADS per block.
// Support (cnt/idx) depends only on r: share CSR across heads; 8 parallel
// entmax solves (2 per wave); PV over full 1024-dim V rows.
__global__ void __launch_bounds__(256) k_attn8(const _Float16* __restrict__ qk16,
                                               const _Float16* __restrict__ val16,
                                               const unsigned* __restrict__ cnt,
                                               const unsigned* __restrict__ idxbuf,
                                               float* __restrict__ attout) {
    __shared__ float ssc[NH][MAXNNZ];     // 12 KB
    __shared__ unsigned sidx[MAXNNZ];     // 1.5 KB
    __shared__ float pvs[2][HD];          // 8 KB
    int l = blockIdx.x;
    int bid = (l & 7) * 512 + (l >> 3);   // XCD swizzle (4096 = 8 * 512, bijective)
    int r = bid & (S_LEN - 1);
    int b = bid >> 11;
    int tid = threadIdx.x;
    int lane = tid & 63;
    int wave = tid >> 6;
    int n = (int)cnt[r];
    const float scale = 0.08838834764831843f;  // 1/sqrt(128)

    for (int j = tid; j < n; j += 256) sidx[j] = idxbuf[r * MAXNNZ + j];
    __syncthreads();

    // ---- phase 1: scores for all 8 heads; group g=(col-slot jj, head h)
    {
        int g  = tid >> 2;           // 0..63
        int jj = g >> 3;             // col slot 0..7
        int h  = g & 7;              // head
        int ll = tid & 3;
        const uint4* q16 = reinterpret_cast<const uint4*>(
                               qk16 + ((size_t)(b * S_LEN + r)) * OCH + h * 128);
        uint4 qreg[4];
#pragma unroll
        for (int i = 0; i < 4; i++) qreg[i] = q16[i * 4 + ll];
        const _Float16* kbase = qk16 + (size_t)b * S_LEN * OCH + HD + h * 128;
        for (int j = jj; j < n; j += 8) {
            const uint4* kp = reinterpret_cast<const uint4*>(kbase + (size_t)sidx[j] * OCH);
            float p = 0.f;
#pragma unroll
            for (int i = 0; i < 4; i++) {
                uint4 kv = kp[i * 4 + ll];
                const unsigned* ka = reinterpret_cast<const unsigned*>(&kv);
                const unsigned* qa = reinterpret_cast<const unsigned*>(&qreg[i]);
                p = dot2acc(qa[0], ka[0], p);
                p = dot2acc(qa[1], ka[1], p);
                p = dot2acc(qa[2], ka[2], p);
                p = dot2acc(qa[3], ka[3], p);
            }
            p += __shfl_xor(p, 1, 64);
            p += __shfl_xor(p, 2, 64);
            if (ll == 0) ssc[h][j] = p * scale;
        }
    }
    __syncthreads();

    // ---- phase 2: entmax per head; wave w solves heads 2w, 2w+1 (all waves busy)
    {
        int nl = (n + 63) >> 6;      // 1..6 slices
        for (int hh = 0; hh < 2; hh++) {
            int h = wave * 2 + hh;
            float xl[6];
            float mx = -3.0e38f;
            for (int l2 = 0; l2 < nl; l2++) {
                int j = lane + (l2 << 6);
                xl[l2] = (j < n) ? ssc[h][j] : -3.0e38f;
                mx = fmaxf(mx, xl[l2]);
            }
#pragma unroll
            for (int off = 32; off >= 1; off >>= 1) mx = fmaxf(mx, __shfl_xor(mx, off, 64));
            for (int l2 = 0; l2 < nl; l2++) xl[l2] = (xl[l2] - mx) * 0.5f;
            float lo = -1.f, hi = 0.f;
            for (int it = 0; it < 26; it++) {
                float mid = 0.5f * (lo + hi);
                float f = 0.f;
                for (int l2 = 0; l2 < nl; l2++) {
                    float d = fmaxf(xl[l2] - mid, 0.f);
                    f += d * d;
                }
#pragma unroll
                for (int off = 32; off >= 1; off >>= 1) f += __shfl_xor(f, off, 64);
                if (f > 1.f) lo = mid; else hi = mid;
            }
            float tau = 0.5f * (lo + hi);
            for (int l2 = 0; l2 < nl; l2++) {
                int j = lane + (l2 << 6);
                if (j < n) {
                    float d = fmaxf(xl[l2] - tau, 0.f);
                    ssc[h][j] = d * d;
                }
            }
        }
    }
    __syncthreads();

    // ---- phase 3: PV over full 1024-dim V rows; thread owns 8 dims, 2 col-halves
    {
        int half = tid >> 7;         // 0..1
        int d = tid & 127;           // dim-group: dims d*8 .. d*8+7
        int h = d >> 4;              // head owning these dims
        const uint4* vbase = reinterpret_cast<const uint4*>(
                                 val16 + (size_t)b * S_LEN * HD) + d;
        float acc[8];
#pragma unroll
        for (int k = 0; k < 8; k++) acc[k] = 0.f;
        for (int j = half; j < n; j += 2) {
            float w = ssc[h][j];
            uint4 vv = vbase[(size_t)sidx[j] << 7];     // row stride 1024 halves = 128 uint4
            const __half2* va = reinterpret_cast<const __half2*>(&vv);
#pragma unroll
            for (int k = 0; k < 4; k++) {
                float2 f = __half22float2(va[k]);
                acc[2 * k]     += w * f.x;
                acc[2 * k + 1] += w * f.y;
            }
        }
#pragma unroll
        for (int k = 0; k < 8; k++) pvs[half][d * 8 + k] = acc[k];
    }
    __syncthreads();
    {
        size_t obase = ((size_t)(b * S_LEN + r)) * HD;
        for (int o = tid; o < HD; o += 256)
            attout[obase + o] = pvs[0][o] + pvs[1][o];
    }
}

// ---------------- out = attout @ w_proj + b_proj, store FLOAT32
// grid BATCH*S/16, block 256 (2-way split-K x 128 cols)
__global__ void k_proj(const float* __restrict__ ao, const float* __restrict__ wp,
                       const float* __restrict__ bp, float* __restrict__ out) {
    __shared__ float xs[2][16][128];
    int bs0 = blockIdx.x * 16;
    int tid = threadIdx.x;
    int dout = tid & 127;
    int kh = tid >> 7;
    float acc[16];
#pragma unroll
    for (int r = 0; r < 16; r++) acc[r] = 0.f;
    for (int cc = 0; cc < 4; cc++) {
        int kb = (kh + 2 * cc) * 128;
        __syncthreads();
        for (int t = dout; t < 16 * 128; t += 128)
            xs[kh][t >> 7][t & 127] = ao[(size_t)(bs0 + (t >> 7)) * HD + kb + (t & 127)];
        __syncthreads();
        for (int k = 0; k < 128; k += 4) {
            float w0 = wp[(kb + k + 0) * DIM + dout];
            float w1 = wp[(kb + k + 1) * DIM + dout];
            float w2 = wp[(kb + k + 2) * DIM + dout];
            float w3 = wp[(kb + k + 3) * DIM + dout];
#pragma unroll
            for (int r = 0; r < 16; r++) {
                float4 xv = *reinterpret_cast<const float4*>(&xs[kh][r][k]);
                acc[r] += xv.x * w0 + xv.y * w1 + xv.z * w2 + xv.w * w3;
            }
        }
    }
    __syncthreads();
#pragma unroll
    for (int r = 0; r < 16; r++) xs[kh][r][dout] = acc[r];
    __syncthreads();
    if (kh == 0) {
        float bb = bp[dout];
        for (int r = 0; r < 16; r++)
            out[(size_t)(bs0 + r) * DIM + dout] = xs[0][r][dout] + xs[1][r][dout] + bb;
    }
}

extern "C" void kernel_launch(void* const* d_in, const int* in_sizes, int n_in,
                              void* d_out, int out_size, void* d_ws, size_t ws_size,
                              hipStream_t stream) {
    const float* x      = (const float*)d_in[0];
    const float* mask   = (const float*)d_in[1];
    const float* w_qk   = (const float*)d_in[2];
    const float* b_qk   = (const float*)d_in[3];
    const float* w_v    = (const float*)d_in[4];
    const float* b_v    = (const float*)d_in[5];
    const float* w_proj = (const float*)d_in[6];
    const float* b_proj = (const float*)d_in[7];
    float* out = (float*)d_out;     // reference output dtype is FLOAT32

    char* ws = (char*)d_ws;
    _Float16*  x16   = (_Float16*)(ws + 0);         //  1,048,576 B
    _Float16*  qk16  = (_Float16*)(ws + 1048576);   // 16,777,216 B
    _Float16*  val16 = (_Float16*)(ws + 17825792);  //  8,388,608 B
    unsigned*  wtp   = (unsigned*)(ws + 26214400);  //  2,621,440 B
    unsigned*  wvp   = (unsigned*)(ws + 28835840);  //    262,144 B
    unsigned*  cnt   = (unsigned*)(ws + 29097984);  //      8,192 B
    unsigned*  idx   = (unsigned*)(ws + 29106176);  //  3,145,728 B
    float*     ao    = (float*)(ws + 32251904);     // 16,777,216 B -> end 49,029,120

    hipLaunchKernelGGL(k_cvt_x, dim3(BATCH * S_LEN * DIM / 4 / 256), dim3(256), 0, stream,
                       (const float4*)x, (ushort4*)x16, BATCH * S_LEN * DIM / 4);
    hipLaunchKernelGGL(k_wqk_pair, dim3((KKTOT / 2) * OCH / 256), dim3(256), 0, stream, w_qk, wtp);
    hipLaunchKernelGGL(k_wv_pair, dim3((DIM / 2) * HD / 256), dim3(256), 0, stream, w_v, wvp);
    hipLaunchKernelGGL(k_mask_csr, dim3(S_LEN), dim3(256), 0, stream, mask, cnt, idx);
    hipLaunchKernelGGL(k_value16, dim3((BATCH * S_LEN) / 16, 4), dim3(256), 0, stream,
                       (const unsigned*)x16, wvp, b_v, val16);
    hipLaunchKernelGGL(k_qkconv16, dim3((BATCH * S_LEN) / 32, 8), dim3(256), 0, stream,
                       (const unsigned*)x16, wtp, b_qk, qk16);
    hipLaunchKernelGGL(k_attn8, dim3(BATCH * S_LEN), dim3(256), 0, stream, qk16, val16, cnt, idx, ao);
    hipLaunchKernelGGL(k_proj, dim3((BATCH * S_LEN) / 16), dim3(256), 0, stream, ao, w_proj, b_proj, out);
}

// Round 21
// 391.955 us; speedup vs baseline: 1.2442x; 1.2442x over previous
//
#include <hip/hip_runtime.h>
#include <hip/hip_bf16.h>
#include <hip/hip_fp16.h>

#define S_LEN 2048
#define BATCH 2
#define DIM 128
#define NH 8
#define HD 1024
#define QL 5
#define KKTOT 640   // DIM*QL
#define OCH 2048
#define MAXNNZ 384

typedef _Float16 hv2 __attribute__((ext_vector_type(2)));

#if defined(__has_builtin)
#  if __has_builtin(__builtin_amdgcn_fdot2)
#    define USE_FDOT2 1
#  endif
#endif
#ifndef USE_FDOT2
#  define USE_FDOT2 0
#endif

__device__ __forceinline__ hv2 u2h(unsigned u) {
    union { unsigned u; hv2 h; } c; c.u = u; return c.h;
}
__device__ __forceinline__ float dot2acc(unsigned a, unsigned b, float acc) {
#if USE_FDOT2
    return __builtin_amdgcn_fdot2(u2h(a), u2h(b), acc, false);
#else
    hv2 ha = u2h(a), hb = u2h(b);
    return acc + (float)ha[0] * (float)hb[0] + (float)ha[1] * (float)hb[1];
#endif
}

// ---------------- x (fp32) -> x16 (fp16)
__global__ void k_cvt_x(const float4* __restrict__ src, ushort4* __restrict__ dst, int n4) {
    int i = blockIdx.x * 256 + threadIdx.x;
    if (i >= n4) return;
    float4 v = src[i];
    ushort4 o;
    o.x = __half_as_ushort(__float2half(v.x));
    o.y = __half_as_ushort(__float2half(v.y));
    o.z = __half_as_ushort(__float2half(v.z));
    o.w = __half_as_ushort(__float2half(v.w));
    dst[i] = o;
}

// ---------------- w_qk (O,I,T) -> paired fp16: wtp[(p*QL+t)*OCH + o] = {w[o,2p,t], w[o,2p+1,t]}
__global__ void k_wqk_pair(const float* __restrict__ w, unsigned* __restrict__ wtp) {
    int j = blockIdx.x * 256 + threadIdx.x;   // 320*2048
    if (j >= (KKTOT / 2) * OCH) return;
    int o = j & 2047;
    int pt = j >> 11;            // p*5 + t
    int p = pt / QL, t = pt % QL;
    float a = w[(size_t)o * KKTOT + (2 * p) * QL + t];
    float b = w[(size_t)o * KKTOT + (2 * p + 1) * QL + t];
    unsigned lo = __half_as_ushort(__float2half(a));
    unsigned hi = __half_as_ushort(__float2half(b));
    wtp[j] = lo | (hi << 16);
}

// ---------------- w_v (128,1024) -> paired fp16: wvp[p*HD + c] = {wv[2p,c], wv[2p+1,c]}
__global__ void k_wv_pair(const float* __restrict__ wv, unsigned* __restrict__ wvp) {
    int j = blockIdx.x * 256 + threadIdx.x;   // 64*1024
    if (j >= (DIM / 2) * HD) return;
    int c = j & 1023;
    int p = j >> 10;
    float a = wv[(size_t)(2 * p) * HD + c];
    float b = wv[(size_t)(2 * p + 1) * HD + c];
    unsigned lo = __half_as_ushort(__float2half(a));
    unsigned hi = __half_as_ushort(__float2half(b));
    wvp[j] = lo | (hi << 16);
}

// ---------------- compact mask rows to CSR (deterministic ballot compaction)
__global__ void k_mask_csr(const float* __restrict__ mask, unsigned* __restrict__ cnt,
                           unsigned* __restrict__ idx) {
    __shared__ unsigned s_base;
    __shared__ unsigned s_wcnt[4];
    int r = blockIdx.x;
    int tid = threadIdx.x;
    int lane = tid & 63;
    int w = tid >> 6;
    if (tid == 0) s_base = 0;
    __syncthreads();
    for (int c0 = 0; c0 < S_LEN; c0 += 256) {
        int c = c0 + tid;
        bool act = mask[(size_t)r * S_LEN + c] > 0.5f;
        unsigned long long bal = __ballot(act);
        if (lane == 0) s_wcnt[w] = (unsigned)__popcll(bal);
        __syncthreads();
        unsigned off = s_base;
        for (int i = 0; i < w; i++) off += s_wcnt[i];
        off += (unsigned)__popcll(bal & ((1ull << lane) - 1ull));
        if (act && off < MAXNNZ) idx[r * MAXNNZ + off] = (unsigned)c;
        __syncthreads();
        if (tid == 0) s_base += s_wcnt[0] + s_wcnt[1] + s_wcnt[2] + s_wcnt[3];
        __syncthreads();
    }
    if (tid == 0) cnt[r] = (s_base < MAXNNZ) ? s_base : MAXNNZ;
}

// ---------------- value = x @ w_v + b_v, fp16 in / fp32 acc / fp16 out
// grid (BATCH*S/16, 4), block 256
__global__ void k_value16(const unsigned* __restrict__ x16u, const unsigned* __restrict__ wvp,
                          const float* __restrict__ bv, _Float16* __restrict__ val16) {
    __shared__ unsigned xs[16][64];   // 16 rows x 64 i-pairs
    int bs0 = blockIdx.x * 16;
    int c = blockIdx.y * 256 + threadIdx.x;
    for (int t = threadIdx.x; t < 16 * 64; t += 256)
        xs[t >> 6][t & 63] = x16u[(size_t)(bs0 + (t >> 6)) * 64 + (t & 63)];
    __syncthreads();
    float acc[16];
#pragma unroll
    for (int r = 0; r < 16; r++) acc[r] = 0.f;
    for (int p = 0; p < 64; p++) {
        unsigned w2 = wvp[(size_t)p * HD + c];
#pragma unroll
        for (int r = 0; r < 16; r++) acc[r] = dot2acc(xs[r][p], w2, acc[r]);
    }
    float b = bv[c];
#pragma unroll
    for (int r = 0; r < 16; r++)
        val16[(size_t)(bs0 + r) * HD + c] = (_Float16)(acc[r] + b);
}

// ---------------- qk conv, fp16 in / fp32 acc / fp16 out.  grid (BATCH*S/32, 8)
__global__ void k_qkconv16(const unsigned* __restrict__ x16u, const unsigned* __restrict__ wtp,
                           const float* __restrict__ bqk, _Float16* __restrict__ qk16) {
    __shared__ unsigned xs[36][64];   // 36 rows x 64 i-pairs
    int bs0 = blockIdx.x * 32;
    int b = bs0 >> 11;
    int s0 = bs0 & 2047;
    int o = blockIdx.y * 256 + threadIdx.x;
    for (int t = threadIdx.x; t < 36 * 64; t += 256) {
        int rr = t >> 6, p = t & 63;
        int s = s0 - 4 + rr;
        xs[rr][p] = (s >= 0) ? x16u[((size_t)b * S_LEN + s) * 64 + p] : 0u;
    }
    __syncthreads();
    float acc[32];
    float bias = bqk[o];
#pragma unroll
    for (int r = 0; r < 32; r++) acc[r] = bias;
    for (int p = 0; p < 64; p++) {
        unsigned xr[36];
#pragma unroll
        for (int rr = 0; rr < 36; rr++) xr[rr] = xs[rr][p];
#pragma unroll
        for (int t = 0; t < QL; t++) {
            unsigned w2 = wtp[(size_t)(p * QL + t) * OCH + o];
#pragma unroll
            for (int r = 0; r < 32; r++)
                acc[r] = dot2acc(xr[r + t], w2, acc[r]);
        }
    }
    for (int r = 0; r < 32; r++)
        qk16[((size_t)bs0 + r) * OCH + o] = (_Float16)acc[r];
}

// ---------------- sparse attention + entmax15 (r19 structure, per-head blocks)
// Phase 2: fused max + Newton-from-below (12 iters) on wave 0.
__global__ void __launch_bounds__(256) k_attn(const _Float16* __restrict__ qk16,
                                              const _Float16* __restrict__ val16,
                                              const unsigned* __restrict__ cnt,
                                              const unsigned* __restrict__ idxbuf,
                                              float* __restrict__ attout) {
    __shared__ float ssc[MAXNNZ];
    __shared__ unsigned sidx[MAXNNZ];
    __shared__ float pvs[16][128];
    int l = blockIdx.x;
    int bid = (l & 7) * 4096 + (l >> 3);   // XCD swizzle (32768 = 8 * 4096, bijective)
    int r = bid & (S_LEN - 1);
    int h = (bid >> 11) & (NH - 1);
    int b = bid >> 14;
    int tid = threadIdx.x;
    int lane = tid & 63;
    int wave = tid >> 6;
    int n = (int)cnt[r];
    const float scale = 0.08838834764831843f;  // 1/sqrt(128)

    for (int j = tid; j < n; j += 256) sidx[j] = idxbuf[r * MAXNNZ + j];
    __syncthreads();

    // ---- phase 1: scores; fp16 q in registers, fp16 K gathers, packed dot
    {
        int grp = tid >> 2;          // 0..63
        int ll  = tid & 3;           // lane within group
        const uint4* q16 = reinterpret_cast<const uint4*>(
                               qk16 + ((size_t)(b * S_LEN + r)) * OCH + h * 128);
        uint4 qreg[4];
#pragma unroll
        for (int i = 0; i < 4; i++) qreg[i] = q16[i * 4 + ll];
        const _Float16* kbase = qk16 + (size_t)b * S_LEN * OCH + HD + h * 128;
        for (int j = grp; j < n; j += 64) {
            const uint4* kp = reinterpret_cast<const uint4*>(kbase + (size_t)sidx[j] * OCH);
            float p = 0.f;
#pragma unroll
            for (int i = 0; i < 4; i++) {
                uint4 kv = kp[i * 4 + ll];
                const unsigned* ka = reinterpret_cast<const unsigned*>(&kv);
                const unsigned* qa = reinterpret_cast<const unsigned*>(&qreg[i]);
                p = dot2acc(qa[0], ka[0], p);
                p = dot2acc(qa[1], ka[1], p);
                p = dot2acc(qa[2], ka[2], p);
                p = dot2acc(qa[3], ka[3], p);
            }
            p += __shfl_xor(p, 1, 64);
            p += __shfl_xor(p, 2, 64);
            if (ll == 0) ssc[j] = p * scale;
        }
    }
    __syncthreads();

    // ---- phase 2: entmax tau on wave 0 — fused max + Newton-from-below (12 it)
    // f(tau) = sum((x - tau)_+^2) with x = score/2; root in [xmax-1, xmax).
    // Newton from tau0 = xmax-1 is monotone increasing, never overshoots
    // (f convex decreasing, s1 >= 1 on [tau0, root]).
    if (wave == 0) {
        float xl[6];
        float mx = -3.0e38f;
#pragma unroll
        for (int l2 = 0; l2 < 6; l2++) {
            int j = lane + 64 * l2;
            xl[l2] = (j < n) ? ssc[j] * 0.5f : -3.0e38f;
            mx = fmaxf(mx, xl[l2]);
        }
#pragma unroll
        for (int off = 32; off >= 1; off >>= 1) mx = fmaxf(mx, __shfl_xor(mx, off, 64));
        float tau = mx - 1.f;
        for (int it = 0; it < 12; it++) {
            float s1 = 0.f, s2 = 0.f;
#pragma unroll
            for (int l2 = 0; l2 < 6; l2++) {
                float d = fmaxf(xl[l2] - tau, 0.f);
                s1 += d;
                s2 += d * d;
            }
#pragma unroll
            for (int off = 32; off >= 1; off >>= 1) {
                s1 += __shfl_xor(s1, off, 64);
                s2 += __shfl_xor(s2, off, 64);
            }
            tau += (s2 - 1.f) / (2.f * s1);
        }
#pragma unroll
        for (int l2 = 0; l2 < 6; l2++) {
            int j = lane + 64 * l2;
            if (j < n) {
                float d = fmaxf(xl[l2] - tau, 0.f);
                ssc[j] = d * d;
            }
        }
    }
    __syncthreads();

    // ---- phase 3: PV, fp16 V — 16 column-slots x 16 dim-groups (8 dims each)
    {
        int slot = tid >> 4;         // 0..15
        int dg   = tid & 15;         // 0..15, dims dg*8..dg*8+7
        const uint4* vbase = reinterpret_cast<const uint4*>(
                                 val16 + (size_t)b * S_LEN * HD + h * 128) + dg;
        float acc[8];
#pragma unroll
        for (int k = 0; k < 8; k++) acc[k] = 0.f;
        for (int j = slot; j < n; j += 16) {
            float w = ssc[j];
            uint4 vv = vbase[(size_t)sidx[j] << 7];     // row stride 1024 halves = 128 uint4
            const __half2* va = reinterpret_cast<const __half2*>(&vv);
#pragma unroll
            for (int k = 0; k < 4; k++) {
                float2 f = __half22float2(va[k]);
                acc[2 * k]     += w * f.x;
                acc[2 * k + 1] += w * f.y;
            }
        }
#pragma unroll
        for (int k = 0; k < 8; k++) pvs[slot][dg * 8 + k] = acc[k];
    }
    __syncthreads();
    if (tid < 128) {
        float a = 0.f;
#pragma unroll
        for (int s = 0; s < 16; s++) a += pvs[s][tid];
        attout[((size_t)(b * S_LEN + r)) * HD + h * 128 + tid] = a;
    }
}

// ---------------- out = attout @ w_proj + b_proj, store FLOAT32
// grid BATCH*S/16, block 256 (2-way split-K x 128 cols)
__global__ void k_proj(const float* __restrict__ ao, const float* __restrict__ wp,
                       const float* __restrict__ bp, float* __restrict__ out) {
    __shared__ float xs[2][16][128];
    int bs0 = blockIdx.x * 16;
    int tid = threadIdx.x;
    int dout = tid & 127;
    int kh = tid >> 7;
    float acc[16];
#pragma unroll
    for (int r = 0; r < 16; r++) acc[r] = 0.f;
    for (int cc = 0; cc < 4; cc++) {
        int kb = (kh + 2 * cc) * 128;
        __syncthreads();
        for (int t = dout; t < 16 * 128; t += 128)
            xs[kh][t >> 7][t & 127] = ao[(size_t)(bs0 + (t >> 7)) * HD + kb + (t & 127)];
        __syncthreads();
        for (int k = 0; k < 128; k += 4) {
            float w0 = wp[(kb + k + 0) * DIM + dout];
            float w1 = wp[(kb + k + 1) * DIM + dout];
            float w2 = wp[(kb + k + 2) * DIM + dout];
            float w3 = wp[(kb + k + 3) * DIM + dout];
#pragma unroll
            for (int r = 0; r < 16; r++) {
                float4 xv = *reinterpret_cast<const float4*>(&xs[kh][r][k]);
                acc[r] += xv.x * w0 + xv.y * w1 + xv.z * w2 + xv.w * w3;
            }
        }
    }
    __syncthreads();
#pragma unroll
    for (int r = 0; r < 16; r++) xs[kh][r][dout] = acc[r];
    __syncthreads();
    if (kh == 0) {
        float bb = bp[dout];
        for (int r = 0; r < 16; r++)
            out[(size_t)(bs0 + r) * DIM + dout] = xs[0][r][dout] + xs[1][r][dout] + bb;
    }
}

extern "C" void kernel_launch(void* const* d_in, const int* in_sizes, int n_in,
                              void* d_out, int out_size, void* d_ws, size_t ws_size,
                              hipStream_t stream) {
    const float* x      = (const float*)d_in[0];
    const float* mask   = (const float*)d_in[1];
    const float* w_qk   = (const float*)d_in[2];
    const float* b_qk   = (const float*)d_in[3];
    const float* w_v    = (const float*)d_in[4];
    const float* b_v    = (const float*)d_in[5];
    const float* w_proj = (const float*)d_in[6];
    const float* b_proj = (const float*)d_in[7];
    float* out = (float*)d_out;     // reference output dtype is FLOAT32

    char* ws = (char*)d_ws;
    _Float16*  x16   = (_Float16*)(ws + 0);         //  1,048,576 B
    _Float16*  qk16  = (_Float16*)(ws + 1048576);   // 16,777,216 B
    _Float16*  val16 = (_Float16*)(ws + 17825792);  //  8,388,608 B
    unsigned*  wtp   = (unsigned*)(ws + 26214400);  //  2,621,440 B
    unsigned*  wvp   = (unsigned*)(ws + 28835840);  //    262,144 B
    unsigned*  cnt   = (unsigned*)(ws + 29097984);  //      8,192 B
    unsigned*  idx   = (unsigned*)(ws + 29106176);  //  3,145,728 B
    float*     ao    = (float*)(ws + 32251904);     // 16,777,216 B -> end 49,029,120

    hipLaunchKernelGGL(k_cvt_x, dim3(BATCH * S_LEN * DIM / 4 / 256), dim3(256), 0, stream,
                       (const float4*)x, (ushort4*)x16, BATCH * S_LEN * DIM / 4);
    hipLaunchKernelGGL(k_wqk_pair, dim3((KKTOT / 2) * OCH / 256), dim3(256), 0, stream, w_qk, wtp);
    hipLaunchKernelGGL(k_wv_pair, dim3((DIM / 2) * HD / 256), dim3(256), 0, stream, w_v, wvp);
    hipLaunchKernelGGL(k_mask_csr, dim3(S_LEN), dim3(256), 0, stream, mask, cnt, idx);
    hipLaunchKernelGGL(k_value16, dim3((BATCH * S_LEN) / 16, 4), dim3(256), 0, stream,
                       (const unsigned*)x16, wvp, b_v, val16);
    hipLaunchKernelGGL(k_qkconv16, dim3((BATCH * S_LEN) / 32, 8), dim3(256), 0, stream,
                       (const unsigned*)x16, wtp, b_qk, qk16);
    hipLaunchKernelGGL(k_attn, dim3(BATCH * NH * S_LEN), dim3(256), 0, stream, qk16, val16, cnt, idx, ao);
    hipLaunchKernelGGL(k_proj, dim3((BATCH * S_LEN) / 16), dim3(256), 0, stream, ao, w_proj, b_proj, out);
}

// Round 22
// 355.551 us; speedup vs baseline: 1.3715x; 1.1024x over previous
//
#include <hip/hip_runtime.h>
#include <hip/hip_bf16.h>
#include <hip/hip_fp16.h>

#define S_LEN 2048
#define BATCH 2
#define DIM 128
#define NH 8
#define HD 1024
#define QL 5
#define KKTOT 640   // DIM*QL
#define OCH 2048
#define MAXNNZ 384

typedef _Float16 hv2 __attribute__((ext_vector_type(2)));
typedef _Float16 f16x8 __attribute__((ext_vector_type(8)));
typedef float f32x4 __attribute__((ext_vector_type(4)));

#if defined(__has_builtin)
#  if __has_builtin(__builtin_amdgcn_fdot2)
#    define USE_FDOT2 1
#  endif
#endif
#ifndef USE_FDOT2
#  define USE_FDOT2 0
#endif

__device__ __forceinline__ hv2 u2h(unsigned u) {
    union { unsigned u; hv2 h; } c; c.u = u; return c.h;
}
__device__ __forceinline__ float dot2acc(unsigned a, unsigned b, float acc) {
#if USE_FDOT2
    return __builtin_amdgcn_fdot2(u2h(a), u2h(b), acc, false);
#else
    hv2 ha = u2h(a), hb = u2h(b);
    return acc + (float)ha[0] * (float)hb[0] + (float)ha[1] * (float)hb[1];
#endif
}

// ---------------- x (fp32) -> x16 (fp16)
__global__ void k_cvt_x(const float4* __restrict__ src, ushort4* __restrict__ dst, int n4) {
    int i = blockIdx.x * 256 + threadIdx.x;
    if (i >= n4) return;
    float4 v = src[i];
    ushort4 o;
    o.x = __half_as_ushort(__float2half(v.x));
    o.y = __half_as_ushort(__float2half(v.y));
    o.z = __half_as_ushort(__float2half(v.z));
    o.w = __half_as_ushort(__float2half(v.w));
    dst[i] = o;
}

// ---------------- w_qk (O,I,T) -> bt16[o][k], k = t*128 + i (t-major K order)
__global__ void k_wqk_t(const float* __restrict__ w, _Float16* __restrict__ bt) {
    int j = blockIdx.x * 256 + threadIdx.x;   // 2048*640
    if (j >= OCH * KKTOT) return;
    int o = j / KKTOT;
    int k = j % KKTOT;
    int t = k >> 7, i = k & 127;
    bt[j] = (_Float16)w[(size_t)o * KKTOT + i * QL + t];
}

// ---------------- w_v (128,1024) -> wvt[c][k] = wv[k][c]
__global__ void k_wv_t(const float* __restrict__ wv, _Float16* __restrict__ wvt) {
    int j = blockIdx.x * 256 + threadIdx.x;   // 1024*128
    if (j >= HD * DIM) return;
    int c = j >> 7, k = j & 127;
    wvt[j] = (_Float16)wv[(size_t)k * HD + c];
}

// ---------------- compact mask rows to CSR (deterministic ballot compaction)
__global__ void k_mask_csr(const float* __restrict__ mask, unsigned* __restrict__ cnt,
                           unsigned* __restrict__ idx) {
    __shared__ unsigned s_base;
    __shared__ unsigned s_wcnt[4];
    int r = blockIdx.x;
    int tid = threadIdx.x;
    int lane = tid & 63;
    int w = tid >> 6;
    if (tid == 0) s_base = 0;
    __syncthreads();
    for (int c0 = 0; c0 < S_LEN; c0 += 256) {
        int c = c0 + tid;
        bool act = mask[(size_t)r * S_LEN + c] > 0.5f;
        unsigned long long bal = __ballot(act);
        if (lane == 0) s_wcnt[w] = (unsigned)__popcll(bal);
        __syncthreads();
        unsigned off = s_base;
        for (int i = 0; i < w; i++) off += s_wcnt[i];
        off += (unsigned)__popcll(bal & ((1ull << lane) - 1ull));
        if (act && off < MAXNNZ) idx[r * MAXNNZ + off] = (unsigned)c;
        __syncthreads();
        if (tid == 0) s_base += s_wcnt[0] + s_wcnt[1] + s_wcnt[2] + s_wcnt[3];
        __syncthreads();
    }
    if (tid == 0) cnt[r] = (s_base < MAXNNZ) ? s_base : MAXNNZ;
}

// ---------------- register-MFMA GEMM: C[4096][NN] = A(x16/im2col) x Bt^T + bias
// 64x64 tile, 4 waves (2x2), each wave four 16x16 accs; frags loaded b128 from
// global (t-major K order keeps each 32-K-step within ONE conv tap -> A rows
// are contiguous x16 rows). No LDS.
template<bool CONV, int KSTEPS, int NN>
__global__ void __launch_bounds__(256) k_gemm16(const _Float16* __restrict__ A,
                                                const _Float16* __restrict__ Bt,
                                                const float* __restrict__ bias,
                                                _Float16* __restrict__ C) {
    const int K = KSTEPS * 32;
    int tid = threadIdx.x;
    int lane = tid & 63, wave = tid >> 6;
    int wr = wave >> 1, wc = wave & 1;
    int l15 = lane & 15, lk = lane >> 4;
    int rbase = blockIdx.x * 64;            // global row base
    int batch = rbase >> 11;
    int s0 = rbase & 2047;                  // batch-local row base
    f32x4 acc[2][2] = {};
    for (int ks = 0; ks < KSTEPS; ks++) {
        int t = CONV ? (ks >> 2) : 0;
        int i0 = CONV ? ((ks & 3) * 32) : (ks * 32);
        f16x8 afr[2], bfr[2];
#pragma unroll
        for (int a = 0; a < 2; a++) {
            int srow = s0 + wr * 32 + a * 16 + l15;
            int sx = CONV ? (srow - (QL - 1) + t) : srow;
            int sclamp = sx < 0 ? 0 : sx;
            f16x8 av = *reinterpret_cast<const f16x8*>(
                A + ((size_t)(batch * S_LEN + sclamp)) * DIM + i0 + lk * 8);
            if (CONV && sx < 0) av = f16x8{0, 0, 0, 0, 0, 0, 0, 0};
            afr[a] = av;
        }
#pragma unroll
        for (int bb = 0; bb < 2; bb++) {
            int col = blockIdx.y * 64 + wc * 32 + bb * 16 + l15;
            bfr[bb] = *reinterpret_cast<const f16x8*>(Bt + (size_t)col * K + ks * 32 + lk * 8);
        }
#pragma unroll
        for (int a = 0; a < 2; a++)
#pragma unroll
            for (int bb = 0; bb < 2; bb++)
                acc[a][bb] = __builtin_amdgcn_mfma_f32_16x16x32_f16(afr[a], bfr[bb], acc[a][bb], 0, 0, 0);
    }
#pragma unroll
    for (int a = 0; a < 2; a++)
#pragma unroll
        for (int bb = 0; bb < 2; bb++) {
            int col = blockIdx.y * 64 + wc * 32 + bb * 16 + l15;
            float bs = bias[col];
#pragma unroll
            for (int j = 0; j < 4; j++) {
                int row = rbase + wr * 32 + a * 16 + lk * 4 + j;   // C/D: row=(lane>>4)*4+j, col=lane&15
                C[(size_t)row * NN + col] = (_Float16)(acc[a][bb][j] + bs);
            }
        }
}

// ---------------- sparse attention + entmax15 (r21: Newton-12 on wave 0)
__global__ void __launch_bounds__(256) k_attn(const _Float16* __restrict__ qk16,
                                              const _Float16* __restrict__ val16,
                                              const unsigned* __restrict__ cnt,
                                              const unsigned* __restrict__ idxbuf,
                                              float* __restrict__ attout) {
    __shared__ float ssc[MAXNNZ];
    __shared__ unsigned sidx[MAXNNZ];
    __shared__ float pvs[16][128];
    int l = blockIdx.x;
    int bid = (l & 7) * 4096 + (l >> 3);   // XCD swizzle (32768 = 8 * 4096, bijective)
    int r = bid & (S_LEN - 1);
    int h = (bid >> 11) & (NH - 1);
    int b = bid >> 14;
    int tid = threadIdx.x;
    int lane = tid & 63;
    int wave = tid >> 6;
    int n = (int)cnt[r];
    const float scale = 0.08838834764831843f;  // 1/sqrt(128)

    for (int j = tid; j < n; j += 256) sidx[j] = idxbuf[r * MAXNNZ + j];
    __syncthreads();

    // ---- phase 1: scores; fp16 q in registers, fp16 K gathers, packed dot
    {
        int grp = tid >> 2;          // 0..63
        int ll  = tid & 3;           // lane within group
        const uint4* q16 = reinterpret_cast<const uint4*>(
                               qk16 + ((size_t)(b * S_LEN + r)) * OCH + h * 128);
        uint4 qreg[4];
#pragma unroll
        for (int i = 0; i < 4; i++) qreg[i] = q16[i * 4 + ll];
        const _Float16* kbase = qk16 + (size_t)b * S_LEN * OCH + HD + h * 128;
        for (int j = grp; j < n; j += 64) {
            const uint4* kp = reinterpret_cast<const uint4*>(kbase + (size_t)sidx[j] * OCH);
            float p = 0.f;
#pragma unroll
            for (int i = 0; i < 4; i++) {
                uint4 kv = kp[i * 4 + ll];
                const unsigned* ka = reinterpret_cast<const unsigned*>(&kv);
                const unsigned* qa = reinterpret_cast<const unsigned*>(&qreg[i]);
                p = dot2acc(qa[0], ka[0], p);
                p = dot2acc(qa[1], ka[1], p);
                p = dot2acc(qa[2], ka[2], p);
                p = dot2acc(qa[3], ka[3], p);
            }
            p += __shfl_xor(p, 1, 64);
            p += __shfl_xor(p, 2, 64);
            if (ll == 0) ssc[j] = p * scale;
        }
    }
    __syncthreads();

    // ---- phase 2: entmax tau on wave 0 — fused max + Newton-from-below (12 it)
    if (wave == 0) {
        float xl[6];
        float mx = -3.0e38f;
#pragma unroll
        for (int l2 = 0; l2 < 6; l2++) {
            int j = lane + 64 * l2;
            xl[l2] = (j < n) ? ssc[j] * 0.5f : -3.0e38f;
            mx = fmaxf(mx, xl[l2]);
        }
#pragma unroll
        for (int off = 32; off >= 1; off >>= 1) mx = fmaxf(mx, __shfl_xor(mx, off, 64));
        float tau = mx - 1.f;
        for (int it = 0; it < 12; it++) {
            float s1 = 0.f, s2 = 0.f;
#pragma unroll
            for (int l2 = 0; l2 < 6; l2++) {
                float d = fmaxf(xl[l2] - tau, 0.f);
                s1 += d;
                s2 += d * d;
            }
#pragma unroll
            for (int off = 32; off >= 1; off >>= 1) {
                s1 += __shfl_xor(s1, off, 64);
                s2 += __shfl_xor(s2, off, 64);
            }
            tau += (s2 - 1.f) / (2.f * s1);
        }
#pragma unroll
        for (int l2 = 0; l2 < 6; l2++) {
            int j = lane + 64 * l2;
            if (j < n) {
                float d = fmaxf(xl[l2] - tau, 0.f);
                ssc[j] = d * d;
            }
        }
    }
    __syncthreads();

    // ---- phase 3: PV, fp16 V — 16 column-slots x 16 dim-groups (8 dims each)
    {
        int slot = tid >> 4;         // 0..15
        int dg   = tid & 15;         // 0..15, dims dg*8..dg*8+7
        const uint4* vbase = reinterpret_cast<const uint4*>(
                                 val16 + (size_t)b * S_LEN * HD + h * 128) + dg;
        float acc[8];
#pragma unroll
        for (int k = 0; k < 8; k++) acc[k] = 0.f;
        for (int j = slot; j < n; j += 16) {
            float w = ssc[j];
            uint4 vv = vbase[(size_t)sidx[j] << 7];     // row stride 1024 halves = 128 uint4
            const __half2* va = reinterpret_cast<const __half2*>(&vv);
#pragma unroll
            for (int k = 0; k < 4; k++) {
                float2 f = __half22float2(va[k]);
                acc[2 * k]     += w * f.x;
                acc[2 * k + 1] += w * f.y;
            }
        }
#pragma unroll
        for (int k = 0; k < 8; k++) pvs[slot][dg * 8 + k] = acc[k];
    }
    __syncthreads();
    if (tid < 128) {
        float a = 0.f;
#pragma unroll
        for (int s = 0; s < 16; s++) a += pvs[s][tid];
        attout[((size_t)(b * S_LEN + r)) * HD + h * 128 + tid] = a;
    }
}

// ---------------- out = attout @ w_proj + b_proj, store FLOAT32
// grid BATCH*S/16, block 256 (2-way split-K x 128 cols)
__global__ void k_proj(const float* __restrict__ ao, const float* __restrict__ wp,
                       const float* __restrict__ bp, float* __restrict__ out) {
    __shared__ float xs[2][16][128];
    int bs0 = blockIdx.x * 16;
    int tid = threadIdx.x;
    int dout = tid & 127;
    int kh = tid >> 7;
    float acc[16];
#pragma unroll
    for (int r = 0; r < 16; r++) acc[r] = 0.f;
    for (int cc = 0; cc < 4; cc++) {
        int kb = (kh + 2 * cc) * 128;
        __syncthreads();
        for (int t = dout; t < 16 * 128; t += 128)
            xs[kh][t >> 7][t & 127] = ao[(size_t)(bs0 + (t >> 7)) * HD + kb + (t & 127)];
        __syncthreads();
        for (int k = 0; k < 128; k += 4) {
            float w0 = wp[(kb + k + 0) * DIM + dout];
            float w1 = wp[(kb + k + 1) * DIM + dout];
            float w2 = wp[(kb + k + 2) * DIM + dout];
            float w3 = wp[(kb + k + 3) * DIM + dout];
#pragma unroll
            for (int r = 0; r < 16; r++) {
                float4 xv = *reinterpret_cast<const float4*>(&xs[kh][r][k]);
                acc[r] += xv.x * w0 + xv.y * w1 + xv.z * w2 + xv.w * w3;
            }
        }
    }
    __syncthreads();
#pragma unroll
    for (int r = 0; r < 16; r++) xs[kh][r][dout] = acc[r];
    __syncthreads();
    if (kh == 0) {
        float bb = bp[dout];
        for (int r = 0; r < 16; r++)
            out[(size_t)(bs0 + r) * DIM + dout] = xs[0][r][dout] + xs[1][r][dout] + bb;
    }
}

extern "C" void kernel_launch(void* const* d_in, const int* in_sizes, int n_in,
                              void* d_out, int out_size, void* d_ws, size_t ws_size,
                              hipStream_t stream) {
    const float* x      = (const float*)d_in[0];
    const float* mask   = (const float*)d_in[1];
    const float* w_qk   = (const float*)d_in[2];
    const float* b_qk   = (const float*)d_in[3];
    const float* w_v    = (const float*)d_in[4];
    const float* b_v    = (const float*)d_in[5];
    const float* w_proj = (const float*)d_in[6];
    const float* b_proj = (const float*)d_in[7];
    float* out = (float*)d_out;     // reference output dtype is FLOAT32

    char* ws = (char*)d_ws;
    _Float16*  x16   = (_Float16*)(ws + 0);         //  1,048,576 B
    _Float16*  qk16  = (_Float16*)(ws + 1048576);   // 16,777,216 B
    _Float16*  val16 = (_Float16*)(ws + 17825792);  //  8,388,608 B
    _Float16*  bt16  = (_Float16*)(ws + 26214400);  //  2,621,440 B  [2048][640]
    _Float16*  wvt   = (_Float16*)(ws + 28835840);  //    262,144 B  [1024][128]
    unsigned*  cnt   = (unsigned*)(ws + 29097984);  //      8,192 B
    unsigned*  idx   = (unsigned*)(ws + 29106176);  //  3,145,728 B
    float*     ao    = (float*)(ws + 32251904);     // 16,777,216 B -> end 49,029,120

    hipLaunchKernelGGL(k_cvt_x, dim3(BATCH * S_LEN * DIM / 4 / 256), dim3(256), 0, stream,
                       (const float4*)x, (ushort4*)x16, BATCH * S_LEN * DIM / 4);
    hipLaunchKernelGGL(k_wqk_t, dim3(OCH * KKTOT / 256), dim3(256), 0, stream, w_qk, bt16);
    hipLaunchKernelGGL(k_wv_t, dim3(HD * DIM / 256), dim3(256), 0, stream, w_v, wvt);
    hipLaunchKernelGGL(k_mask_csr, dim3(S_LEN), dim3(256), 0, stream, mask, cnt, idx);
    hipLaunchKernelGGL((k_gemm16<false, 4, HD>), dim3(BATCH * S_LEN / 64, HD / 64), dim3(256), 0, stream,
                       x16, wvt, b_v, val16);
    hipLaunchKernelGGL((k_gemm16<true, 20, OCH>), dim3(BATCH * S_LEN / 64, OCH / 64), dim3(256), 0, stream,
                       x16, bt16, b_qk, qk16);
    hipLaunchKernelGGL(k_attn, dim3(BATCH * NH * S_LEN), dim3(256), 0, stream, qk16, val16, cnt, idx, ao);
    hipLaunchKernelGGL(k_proj, dim3((BATCH * S_LEN) / 16), dim3(256), 0, stream, ao, w_proj, b_proj, out);
}

// Round 23
// 325.136 us; speedup vs baseline: 1.4998x; 1.0935x over previous
//
#include <hip/hip_runtime.h>
#include <hip/hip_bf16.h>
#include <hip/hip_fp16.h>

#define S_LEN 2048
#define BATCH 2
#define DIM 128
#define NH 8
#define HD 1024
#define QL 5
#define KKTOT 640   // DIM*QL
#define OCH 2048
#define MAXNNZ 384

typedef _Float16 hv2 __attribute__((ext_vector_type(2)));
typedef _Float16 f16x8 __attribute__((ext_vector_type(8)));
typedef float f32x4 __attribute__((ext_vector_type(4)));

#if defined(__has_builtin)
#  if __has_builtin(__builtin_amdgcn_fdot2)
#    define USE_FDOT2 1
#  endif
#endif
#ifndef USE_FDOT2
#  define USE_FDOT2 0
#endif

__device__ __forceinline__ hv2 u2h(unsigned u) {
    union { unsigned u; hv2 h; } c; c.u = u; return c.h;
}
__device__ __forceinline__ float dot2acc(unsigned a, unsigned b, float acc) {
#if USE_FDOT2
    return __builtin_amdgcn_fdot2(u2h(a), u2h(b), acc, false);
#else
    hv2 ha = u2h(a), hb = u2h(b);
    return acc + (float)ha[0] * (float)hb[0] + (float)ha[1] * (float)hb[1];
#endif
}

// ---------------- x (fp32) -> x16 (fp16)
__global__ void k_cvt_x(const float4* __restrict__ src, ushort4* __restrict__ dst, int n4) {
    int i = blockIdx.x * 256 + threadIdx.x;
    if (i >= n4) return;
    float4 v = src[i];
    ushort4 o;
    o.x = __half_as_ushort(__float2half(v.x));
    o.y = __half_as_ushort(__float2half(v.y));
    o.z = __half_as_ushort(__float2half(v.z));
    o.w = __half_as_ushort(__float2half(v.w));
    dst[i] = o;
}

// ---------------- w_qk (O,I,T) -> bt16[o][k], k = t*128 + i (t-major K order)
__global__ void k_wqk_t(const float* __restrict__ w, _Float16* __restrict__ bt) {
    int j = blockIdx.x * 256 + threadIdx.x;   // 2048*640
    if (j >= OCH * KKTOT) return;
    int o = j / KKTOT;
    int k = j % KKTOT;
    int t = k >> 7, i = k & 127;
    bt[j] = (_Float16)w[(size_t)o * KKTOT + i * QL + t];
}

// ---------------- w_v (128,1024) -> wvt[c][k] = wv[k][c]
__global__ void k_wv_t(const float* __restrict__ wv, _Float16* __restrict__ wvt) {
    int j = blockIdx.x * 256 + threadIdx.x;   // 1024*128
    if (j >= HD * DIM) return;
    int c = j >> 7, k = j & 127;
    wvt[j] = (_Float16)wv[(size_t)k * HD + c];
}

// ---------------- w_proj (1024,128) -> wpt[c][k] = wp[k][c]
__global__ void k_wp_t(const float* __restrict__ wp, _Float16* __restrict__ wpt) {
    int j = blockIdx.x * 256 + threadIdx.x;   // 128*1024
    if (j >= DIM * HD) return;
    int c = j >> 10, k = j & 1023;
    wpt[j] = (_Float16)wp[(size_t)k * DIM + c];
}

// ---------------- compact mask rows to CSR (deterministic ballot compaction)
__global__ void k_mask_csr(const float* __restrict__ mask, unsigned* __restrict__ cnt,
                           unsigned* __restrict__ idx) {
    __shared__ unsigned s_base;
    __shared__ unsigned s_wcnt[4];
    int r = blockIdx.x;
    int tid = threadIdx.x;
    int lane = tid & 63;
    int w = tid >> 6;
    if (tid == 0) s_base = 0;
    __syncthreads();
    for (int c0 = 0; c0 < S_LEN; c0 += 256) {
        int c = c0 + tid;
        bool act = mask[(size_t)r * S_LEN + c] > 0.5f;
        unsigned long long bal = __ballot(act);
        if (lane == 0) s_wcnt[w] = (unsigned)__popcll(bal);
        __syncthreads();
        unsigned off = s_base;
        for (int i = 0; i < w; i++) off += s_wcnt[i];
        off += (unsigned)__popcll(bal & ((1ull << lane) - 1ull));
        if (act && off < MAXNNZ) idx[r * MAXNNZ + off] = (unsigned)c;
        __syncthreads();
        if (tid == 0) s_base += s_wcnt[0] + s_wcnt[1] + s_wcnt[2] + s_wcnt[3];
        __syncthreads();
    }
    if (tid == 0) cnt[r] = (s_base < MAXNNZ) ? s_base : MAXNNZ;
}

// ---------------- register-MFMA GEMM: C[4096][NN] = A(x16/im2col) x Bt^T + bias
// 64x64 tile, 4 waves (2x2), each wave four 16x16 accs; frags loaded b128 from
// global. OutT selects the store type (fp16 intermediate / fp32 final).
template<bool CONV, int KSTEPS, int NN, typename OutT>
__global__ void __launch_bounds__(256) k_gemm16(const _Float16* __restrict__ A,
                                                const _Float16* __restrict__ Bt,
                                                const float* __restrict__ bias,
                                                OutT* __restrict__ C) {
    const int K = KSTEPS * 32;
    int tid = threadIdx.x;
    int lane = tid & 63, wave = tid >> 6;
    int wr = wave >> 1, wc = wave & 1;
    int l15 = lane & 15, lk = lane >> 4;
    int rbase = blockIdx.x * 64;            // global row base
    int batch = rbase >> 11;
    int s0 = rbase & 2047;                  // batch-local row base
    f32x4 acc[2][2] = {};
    for (int ks = 0; ks < KSTEPS; ks++) {
        int t = CONV ? (ks >> 2) : 0;
        int i0 = CONV ? ((ks & 3) * 32) : (ks * 32);
        f16x8 afr[2], bfr[2];
#pragma unroll
        for (int a = 0; a < 2; a++) {
            int srow = s0 + wr * 32 + a * 16 + l15;
            int sx = CONV ? (srow - (QL - 1) + t) : srow;
            int sclamp = sx < 0 ? 0 : sx;
            f16x8 av = *reinterpret_cast<const f16x8*>(
                A + ((size_t)(batch * S_LEN + sclamp)) * (CONV ? DIM : (K)) + i0 + lk * 8);
            if (CONV && sx < 0) av = f16x8{0, 0, 0, 0, 0, 0, 0, 0};
            afr[a] = av;
        }
#pragma unroll
        for (int bb = 0; bb < 2; bb++) {
            int col = blockIdx.y * 64 + wc * 32 + bb * 16 + l15;
            bfr[bb] = *reinterpret_cast<const f16x8*>(Bt + (size_t)col * K + ks * 32 + lk * 8);
        }
#pragma unroll
        for (int a = 0; a < 2; a++)
#pragma unroll
            for (int bb = 0; bb < 2; bb++)
                acc[a][bb] = __builtin_amdgcn_mfma_f32_16x16x32_f16(afr[a], bfr[bb], acc[a][bb], 0, 0, 0);
    }
#pragma unroll
    for (int a = 0; a < 2; a++)
#pragma unroll
        for (int bb = 0; bb < 2; bb++) {
            int col = blockIdx.y * 64 + wc * 32 + bb * 16 + l15;
            float bs = bias[col];
#pragma unroll
            for (int j = 0; j < 4; j++) {
                int row = rbase + wr * 32 + a * 16 + lk * 4 + j;   // C/D: row=(lane>>4)*4+j, col=lane&15
                C[(size_t)row * NN + col] = (OutT)(acc[a][bb][j] + bs);
            }
        }
}

// ---------------- sparse attention + entmax15 (Newton-12 on wave 0), fp16 out
__global__ void __launch_bounds__(256) k_attn(const _Float16* __restrict__ qk16,
                                              const _Float16* __restrict__ val16,
                                              const unsigned* __restrict__ cnt,
                                              const unsigned* __restrict__ idxbuf,
                                              _Float16* __restrict__ attout) {
    __shared__ float ssc[MAXNNZ];
    __shared__ unsigned sidx[MAXNNZ];
    __shared__ float pvs[16][128];
    int l = blockIdx.x;
    int bid = (l & 7) * 4096 + (l >> 3);   // XCD swizzle (32768 = 8 * 4096, bijective)
    int r = bid & (S_LEN - 1);
    int h = (bid >> 11) & (NH - 1);
    int b = bid >> 14;
    int tid = threadIdx.x;
    int lane = tid & 63;
    int wave = tid >> 6;
    int n = (int)cnt[r];
    const float scale = 0.08838834764831843f;  // 1/sqrt(128)

    for (int j = tid; j < n; j += 256) sidx[j] = idxbuf[r * MAXNNZ + j];
    __syncthreads();

    // ---- phase 1: scores; fp16 q in registers, fp16 K gathers, packed dot
    {
        int grp = tid >> 2;          // 0..63
        int ll  = tid & 3;           // lane within group
        const uint4* q16 = reinterpret_cast<const uint4*>(
                               qk16 + ((size_t)(b * S_LEN + r)) * OCH + h * 128);
        uint4 qreg[4];
#pragma unroll
        for (int i = 0; i < 4; i++) qreg[i] = q16[i * 4 + ll];
        const _Float16* kbase = qk16 + (size_t)b * S_LEN * OCH + HD + h * 128;
        for (int j = grp; j < n; j += 64) {
            const uint4* kp = reinterpret_cast<const uint4*>(kbase + (size_t)sidx[j] * OCH);
            float p = 0.f;
#pragma unroll
            for (int i = 0; i < 4; i++) {
                uint4 kv = kp[i * 4 + ll];
                const unsigned* ka = reinterpret_cast<const unsigned*>(&kv);
                const unsigned* qa = reinterpret_cast<const unsigned*>(&qreg[i]);
                p = dot2acc(qa[0], ka[0], p);
                p = dot2acc(qa[1], ka[1], p);
                p = dot2acc(qa[2], ka[2], p);
                p = dot2acc(qa[3], ka[3], p);
            }
            p += __shfl_xor(p, 1, 64);
            p += __shfl_xor(p, 2, 64);
            if (ll == 0) ssc[j] = p * scale;
        }
    }
    __syncthreads();

    // ---- phase 2: entmax tau on wave 0 — fused max + Newton-from-below (12 it)
    if (wave == 0) {
        float xl[6];
        float mx = -3.0e38f;
#pragma unroll
        for (int l2 = 0; l2 < 6; l2++) {
            int j = lane + 64 * l2;
            xl[l2] = (j < n) ? ssc[j] * 0.5f : -3.0e38f;
            mx = fmaxf(mx, xl[l2]);
        }
#pragma unroll
        for (int off = 32; off >= 1; off >>= 1) mx = fmaxf(mx, __shfl_xor(mx, off, 64));
        float tau = mx - 1.f;
        for (int it = 0; it < 12; it++) {
            float s1 = 0.f, s2 = 0.f;
#pragma unroll
            for (int l2 = 0; l2 < 6; l2++) {
                float d = fmaxf(xl[l2] - tau, 0.f);
                s1 += d;
                s2 += d * d;
            }
#pragma unroll
            for (int off = 32; off >= 1; off >>= 1) {
                s1 += __shfl_xor(s1, off, 64);
                s2 += __shfl_xor(s2, off, 64);
            }
            tau += (s2 - 1.f) / (2.f * s1);
        }
#pragma unroll
        for (int l2 = 0; l2 < 6; l2++) {
            int j = lane + 64 * l2;
            if (j < n) {
                float d = fmaxf(xl[l2] - tau, 0.f);
                ssc[j] = d * d;
            }
        }
    }
    __syncthreads();

    // ---- phase 3: PV, fp16 V — 16 column-slots x 16 dim-groups (8 dims each)
    {
        int slot = tid >> 4;         // 0..15
        int dg   = tid & 15;         // 0..15, dims dg*8..dg*8+7
        const uint4* vbase = reinterpret_cast<const uint4*>(
                                 val16 + (size_t)b * S_LEN * HD + h * 128) + dg;
        float acc[8];
#pragma unroll
        for (int k = 0; k < 8; k++) acc[k] = 0.f;
        for (int j = slot; j < n; j += 16) {
            float w = ssc[j];
            uint4 vv = vbase[(size_t)sidx[j] << 7];     // row stride 1024 halves = 128 uint4
            const __half2* va = reinterpret_cast<const __half2*>(&vv);
#pragma unroll
            for (int k = 0; k < 4; k++) {
                float2 f = __half22float2(va[k]);
                acc[2 * k]     += w * f.x;
                acc[2 * k + 1] += w * f.y;
            }
        }
#pragma unroll
        for (int k = 0; k < 8; k++) pvs[slot][dg * 8 + k] = acc[k];
    }
    __syncthreads();
    if (tid < 128) {
        float a = 0.f;
#pragma unroll
        for (int s = 0; s < 16; s++) a += pvs[s][tid];
        attout[((size_t)(b * S_LEN + r)) * HD + h * 128 + tid] = (_Float16)a;
    }
}

extern "C" void kernel_launch(void* const* d_in, const int* in_sizes, int n_in,
                              void* d_out, int out_size, void* d_ws, size_t ws_size,
                              hipStream_t stream) {
    const float* x      = (const float*)d_in[0];
    const float* mask   = (const float*)d_in[1];
    const float* w_qk   = (const float*)d_in[2];
    const float* b_qk   = (const float*)d_in[3];
    const float* w_v    = (const float*)d_in[4];
    const float* b_v    = (const float*)d_in[5];
    const float* w_proj = (const float*)d_in[6];
    const float* b_proj = (const float*)d_in[7];
    float* out = (float*)d_out;     // reference output dtype is FLOAT32

    char* ws = (char*)d_ws;
    _Float16*  x16   = (_Float16*)(ws + 0);         //  1,048,576 B
    _Float16*  qk16  = (_Float16*)(ws + 1048576);   // 16,777,216 B
    _Float16*  val16 = (_Float16*)(ws + 17825792);  //  8,388,608 B
    _Float16*  bt16  = (_Float16*)(ws + 26214400);  //  2,621,440 B  [2048][640]
    _Float16*  wvt   = (_Float16*)(ws + 28835840);  //    262,144 B  [1024][128]
    _Float16*  wpt   = (_Float16*)(ws + 29097984);  //    262,144 B  [128][1024]
    unsigned*  cnt   = (unsigned*)(ws + 29360128);  //      8,192 B
    unsigned*  idx   = (unsigned*)(ws + 29368320);  //  3,145,728 B
    _Float16*  ao16  = (_Float16*)(ws + 32514048);  //  8,388,608 B -> end 40,902,656

    hipLaunchKernelGGL(k_cvt_x, dim3(BATCH * S_LEN * DIM / 4 / 256), dim3(256), 0, stream,
                       (const float4*)x, (ushort4*)x16, BATCH * S_LEN * DIM / 4);
    hipLaunchKernelGGL(k_wqk_t, dim3(OCH * KKTOT / 256), dim3(256), 0, stream, w_qk, bt16);
    hipLaunchKernelGGL(k_wv_t, dim3(HD * DIM / 256), dim3(256), 0, stream, w_v, wvt);
    hipLaunchKernelGGL(k_wp_t, dim3(DIM * HD / 256), dim3(256), 0, stream, w_proj, wpt);
    hipLaunchKernelGGL(k_mask_csr, dim3(S_LEN), dim3(256), 0, stream, mask, cnt, idx);
    hipLaunchKernelGGL((k_gemm16<false, 4, HD, _Float16>), dim3(BATCH * S_LEN / 64, HD / 64), dim3(256), 0, stream,
                       x16, wvt, b_v, val16);
    hipLaunchKernelGGL((k_gemm16<true, 20, OCH, _Float16>), dim3(BATCH * S_LEN / 64, OCH / 64), dim3(256), 0, stream,
                       x16, bt16, b_qk, qk16);
    hipLaunchKernelGGL(k_attn, dim3(BATCH * NH * S_LEN), dim3(256), 0, stream, qk16, val16, cnt, idx, ao16);
    hipLaunchKernelGGL((k_gemm16<false, 32, DIM, float>), dim3(BATCH * S_LEN / 64, DIM / 64), dim3(256), 0, stream,
                       ao16, wpt, b_proj, out);
}

// Round 24
// 309.082 us; speedup vs baseline: 1.5777x; 1.0519x over previous
//
#include <hip/hip_runtime.h>
#include <hip/hip_bf16.h>
#include <hip/hip_fp16.h>

#define S_LEN 2048
#define BATCH 2
#define DIM 128
#define NH 8
#define HD 1024
#define QL 5
#define KKTOT 640   // DIM*QL
#define OCH 2048
#define MAXNNZ 384

typedef _Float16 hv2 __attribute__((ext_vector_type(2)));
typedef _Float16 f16x8 __attribute__((ext_vector_type(8)));
typedef float f32x4 __attribute__((ext_vector_type(4)));

#if defined(__has_builtin)
#  if __has_builtin(__builtin_amdgcn_fdot2)
#    define USE_FDOT2 1
#  endif
#endif
#ifndef USE_FDOT2
#  define USE_FDOT2 0
#endif

__device__ __forceinline__ hv2 u2h(unsigned u) {
    union { unsigned u; hv2 h; } c; c.u = u; return c.h;
}
__device__ __forceinline__ float dot2acc(unsigned a, unsigned b, float acc) {
#if USE_FDOT2
    return __builtin_amdgcn_fdot2(u2h(a), u2h(b), acc, false);
#else
    hv2 ha = u2h(a), hb = u2h(b);
    return acc + (float)ha[0] * (float)hb[0] + (float)ha[1] * (float)hb[1];
#endif
}

// ---------------- fused preprocessing: x->fp16, w_qk->bt16 (t-major), w_v/w_proj transpose
// flat index over 2,097,152 = 8192 * 256 elements
__global__ void k_prep(const float* __restrict__ x, const float* __restrict__ w_qk,
                       const float* __restrict__ wv, const float* __restrict__ wp,
                       _Float16* __restrict__ x16, _Float16* __restrict__ bt,
                       _Float16* __restrict__ wvt, _Float16* __restrict__ wpt) {
    int i = blockIdx.x * 256 + threadIdx.x;
    if (i < OCH * KKTOT) {                       // bt16[o][k], k = t*128+i
        int o = i / KKTOT, k = i % KKTOT;
        int t = k >> 7, ii = k & 127;
        bt[i] = (_Float16)w_qk[(size_t)o * KKTOT + ii * QL + t];
        return;
    }
    i -= OCH * KKTOT;
    if (i < BATCH * S_LEN * DIM) {               // x16
        x16[i] = (_Float16)x[i];
        return;
    }
    i -= BATCH * S_LEN * DIM;
    if (i < HD * DIM) {                          // wvt[c][k] = wv[k][c]
        int c = i >> 7, k = i & 127;
        wvt[i] = (_Float16)wv[(size_t)k * HD + c];
        return;
    }
    i -= HD * DIM;
    if (i < DIM * HD) {                          // wpt[c][k] = wp[k][c]
        int c = i >> 10, k = i & 1023;
        wpt[i] = (_Float16)wp[(size_t)k * DIM + c];
    }
}

// ---------------- compact mask rows to CSR (deterministic ballot compaction)
__global__ void k_mask_csr(const float* __restrict__ mask, unsigned* __restrict__ cnt,
                           unsigned* __restrict__ idx) {
    __shared__ unsigned s_base;
    __shared__ unsigned s_wcnt[4];
    int r = blockIdx.x;
    int tid = threadIdx.x;
    int lane = tid & 63;
    int w = tid >> 6;
    if (tid == 0) s_base = 0;
    __syncthreads();
    for (int c0 = 0; c0 < S_LEN; c0 += 256) {
        int c = c0 + tid;
        bool act = mask[(size_t)r * S_LEN + c] > 0.5f;
        unsigned long long bal = __ballot(act);
        if (lane == 0) s_wcnt[w] = (unsigned)__popcll(bal);
        __syncthreads();
        unsigned off = s_base;
        for (int i = 0; i < w; i++) off += s_wcnt[i];
        off += (unsigned)__popcll(bal & ((1ull << lane) - 1ull));
        if (act && off < MAXNNZ) idx[r * MAXNNZ + off] = (unsigned)c;
        __syncthreads();
        if (tid == 0) s_base += s_wcnt[0] + s_wcnt[1] + s_wcnt[2] + s_wcnt[3];
        __syncthreads();
    }
    if (tid == 0) cnt[r] = (s_base < MAXNNZ) ? s_base : MAXNNZ;
}

// ---------------- register-MFMA GEMM: C[4096][NN] = A(x16/im2col) x Bt^T + bias
template<bool CONV, int KSTEPS, int NN, typename OutT>
__global__ void __launch_bounds__(256) k_gemm16(const _Float16* __restrict__ A,
                                                const _Float16* __restrict__ Bt,
                                                const float* __restrict__ bias,
                                                OutT* __restrict__ C) {
    const int K = KSTEPS * 32;
    int tid = threadIdx.x;
    int lane = tid & 63, wave = tid >> 6;
    int wr = wave >> 1, wc = wave & 1;
    int l15 = lane & 15, lk = lane >> 4;
    int rbase = blockIdx.x * 64;            // global row base
    int batch = rbase >> 11;
    int s0 = rbase & 2047;                  // batch-local row base
    f32x4 acc[2][2] = {};
    for (int ks = 0; ks < KSTEPS; ks++) {
        int t = CONV ? (ks >> 2) : 0;
        int i0 = CONV ? ((ks & 3) * 32) : (ks * 32);
        f16x8 afr[2], bfr[2];
#pragma unroll
        for (int a = 0; a < 2; a++) {
            int srow = s0 + wr * 32 + a * 16 + l15;
            int sx = CONV ? (srow - (QL - 1) + t) : srow;
            int sclamp = sx < 0 ? 0 : sx;
            f16x8 av = *reinterpret_cast<const f16x8*>(
                A + ((size_t)(batch * S_LEN + sclamp)) * (CONV ? DIM : (K)) + i0 + lk * 8);
            if (CONV && sx < 0) av = f16x8{0, 0, 0, 0, 0, 0, 0, 0};
            afr[a] = av;
        }
#pragma unroll
        for (int bb = 0; bb < 2; bb++) {
            int col = blockIdx.y * 64 + wc * 32 + bb * 16 + l15;
            bfr[bb] = *reinterpret_cast<const f16x8*>(Bt + (size_t)col * K + ks * 32 + lk * 8);
        }
#pragma unroll
        for (int a = 0; a < 2; a++)
#pragma unroll
            for (int bb = 0; bb < 2; bb++)
                acc[a][bb] = __builtin_amdgcn_mfma_f32_16x16x32_f16(afr[a], bfr[bb], acc[a][bb], 0, 0, 0);
    }
#pragma unroll
    for (int a = 0; a < 2; a++)
#pragma unroll
        for (int bb = 0; bb < 2; bb++) {
            int col = blockIdx.y * 64 + wc * 32 + bb * 16 + l15;
            float bs = bias[col];
#pragma unroll
            for (int j = 0; j < 4; j++) {
                int row = rbase + wr * 32 + a * 16 + lk * 4 + j;   // C/D: row=(lane>>4)*4+j, col=lane&15
                C[(size_t)row * NN + col] = (OutT)(acc[a][bb][j] + bs);
            }
        }
}

// ---------------- sparse attention + entmax15 (Newton-10 on wave 0), fp16 out
// pvs padded [16][136] + float4 stores: <=4-way LDS bank conflict (was 8-16).
__global__ void __launch_bounds__(256) k_attn(const _Float16* __restrict__ qk16,
                                              const _Float16* __restrict__ val16,
                                              const unsigned* __restrict__ cnt,
                                              const unsigned* __restrict__ idxbuf,
                                              _Float16* __restrict__ attout) {
    __shared__ float ssc[MAXNNZ];
    __shared__ unsigned sidx[MAXNNZ];
    __shared__ float pvs[16][136];
    int l = blockIdx.x;
    int bid = (l & 7) * 4096 + (l >> 3);   // XCD swizzle (32768 = 8 * 4096, bijective)
    int r = bid & (S_LEN - 1);
    int h = (bid >> 11) & (NH - 1);
    int b = bid >> 14;
    int tid = threadIdx.x;
    int lane = tid & 63;
    int wave = tid >> 6;
    int n = (int)cnt[r];
    const float scale = 0.08838834764831843f;  // 1/sqrt(128)

    for (int j = tid; j < n; j += 256) sidx[j] = idxbuf[r * MAXNNZ + j];
    __syncthreads();

    // ---- phase 1: scores; fp16 q in registers, fp16 K gathers, packed dot
    {
        int grp = tid >> 2;          // 0..63
        int ll  = tid & 3;           // lane within group
        const uint4* q16 = reinterpret_cast<const uint4*>(
                               qk16 + ((size_t)(b * S_LEN + r)) * OCH + h * 128);
        uint4 qreg[4];
#pragma unroll
        for (int i = 0; i < 4; i++) qreg[i] = q16[i * 4 + ll];
        const _Float16* kbase = qk16 + (size_t)b * S_LEN * OCH + HD + h * 128;
        for (int j = grp; j < n; j += 64) {
            const uint4* kp = reinterpret_cast<const uint4*>(kbase + (size_t)sidx[j] * OCH);
            float p = 0.f;
#pragma unroll
            for (int i = 0; i < 4; i++) {
                uint4 kv = kp[i * 4 + ll];
                const unsigned* ka = reinterpret_cast<const unsigned*>(&kv);
                const unsigned* qa = reinterpret_cast<const unsigned*>(&qreg[i]);
                p = dot2acc(qa[0], ka[0], p);
                p = dot2acc(qa[1], ka[1], p);
                p = dot2acc(qa[2], ka[2], p);
                p = dot2acc(qa[3], ka[3], p);
            }
            p += __shfl_xor(p, 1, 64);
            p += __shfl_xor(p, 2, 64);
            if (ll == 0) ssc[j] = p * scale;
        }
    }
    __syncthreads();

    // ---- phase 2: entmax tau on wave 0 — fused max + Newton-from-below (10 it)
    if (wave == 0) {
        float xl[6];
        float mx = -3.0e38f;
#pragma unroll
        for (int l2 = 0; l2 < 6; l2++) {
            int j = lane + 64 * l2;
            xl[l2] = (j < n) ? ssc[j] * 0.5f : -3.0e38f;
            mx = fmaxf(mx, xl[l2]);
        }
#pragma unroll
        for (int off = 32; off >= 1; off >>= 1) mx = fmaxf(mx, __shfl_xor(mx, off, 64));
        float tau = mx - 1.f;
        for (int it = 0; it < 10; it++) {
            float s1 = 0.f, s2 = 0.f;
#pragma unroll
            for (int l2 = 0; l2 < 6; l2++) {
                float d = fmaxf(xl[l2] - tau, 0.f);
                s1 += d;
                s2 += d * d;
            }
#pragma unroll
            for (int off = 32; off >= 1; off >>= 1) {
                s1 += __shfl_xor(s1, off, 64);
                s2 += __shfl_xor(s2, off, 64);
            }
            tau += (s2 - 1.f) / (2.f * s1);
        }
#pragma unroll
        for (int l2 = 0; l2 < 6; l2++) {
            int j = lane + 64 * l2;
            if (j < n) {
                float d = fmaxf(xl[l2] - tau, 0.f);
                ssc[j] = d * d;
            }
        }
    }
    __syncthreads();

    // ---- phase 3: PV, fp16 V — 16 column-slots x 16 dim-groups (8 dims each)
    {
        int slot = tid >> 4;         // 0..15
        int dg   = tid & 15;         // 0..15, dims dg*8..dg*8+7
        const uint4* vbase = reinterpret_cast<const uint4*>(
                                 val16 + (size_t)b * S_LEN * HD + h * 128) + dg;
        float acc[8];
#pragma unroll
        for (int k = 0; k < 8; k++) acc[k] = 0.f;
        for (int j = slot; j < n; j += 16) {
            float w = ssc[j];
            uint4 vv = vbase[(size_t)sidx[j] << 7];     // row stride 1024 halves = 128 uint4
            const __half2* va = reinterpret_cast<const __half2*>(&vv);
#pragma unroll
            for (int k = 0; k < 4; k++) {
                float2 f = __half22float2(va[k]);
                acc[2 * k]     += w * f.x;
                acc[2 * k + 1] += w * f.y;
            }
        }
        float4 v0 = {acc[0], acc[1], acc[2], acc[3]};
        float4 v1 = {acc[4], acc[5], acc[6], acc[7]};
        *reinterpret_cast<float4*>(&pvs[slot][dg * 8]) = v0;
        *reinterpret_cast<float4*>(&pvs[slot][dg * 8 + 4]) = v1;
    }
    __syncthreads();
    if (tid < 128) {
        float a = 0.f;
#pragma unroll
        for (int s = 0; s < 16; s++) a += pvs[s][tid];
        attout[((size_t)(b * S_LEN + r)) * HD + h * 128 + tid] = (_Float16)a;
    }
}

extern "C" void kernel_launch(void* const* d_in, const int* in_sizes, int n_in,
                              void* d_out, int out_size, void* d_ws, size_t ws_size,
                              hipStream_t stream) {
    const float* x      = (const float*)d_in[0];
    const float* mask   = (const float*)d_in[1];
    const float* w_qk   = (const float*)d_in[2];
    const float* b_qk   = (const float*)d_in[3];
    const float* w_v    = (const float*)d_in[4];
    const float* b_v    = (const float*)d_in[5];
    const float* w_proj = (const float*)d_in[6];
    const float* b_proj = (const float*)d_in[7];
    float* out = (float*)d_out;     // reference output dtype is FLOAT32

    char* ws = (char*)d_ws;
    _Float16*  x16   = (_Float16*)(ws + 0);         //  1,048,576 B
    _Float16*  qk16  = (_Float16*)(ws + 1048576);   // 16,777,216 B
    _Float16*  val16 = (_Float16*)(ws + 17825792);  //  8,388,608 B
    _Float16*  bt16  = (_Float16*)(ws + 26214400);  //  2,621,440 B  [2048][640]
    _Float16*  wvt   = (_Float16*)(ws + 28835840);  //    262,144 B  [1024][128]
    _Float16*  wpt   = (_Float16*)(ws + 29097984);  //    262,144 B  [128][1024]
    unsigned*  cnt   = (unsigned*)(ws + 29360128);  //      8,192 B
    unsigned*  idx   = (unsigned*)(ws + 29368320);  //  3,145,728 B
    _Float16*  ao16  = (_Float16*)(ws + 32514048);  //  8,388,608 B -> end 40,902,656

    hipLaunchKernelGGL(k_prep, dim3(8192), dim3(256), 0, stream,
                       x, w_qk, w_v, w_proj, x16, bt16, wvt, wpt);
    hipLaunchKernelGGL(k_mask_csr, dim3(S_LEN), dim3(256), 0, stream, mask, cnt, idx);
    hipLaunchKernelGGL((k_gemm16<false, 4, HD, _Float16>), dim3(BATCH * S_LEN / 64, HD / 64), dim3(256), 0, stream,
                       x16, wvt, b_v, val16);
    hipLaunchKernelGGL((k_gemm16<true, 20, OCH, _Float16>), dim3(BATCH * S_LEN / 64, OCH / 64), dim3(256), 0, stream,
                       x16, bt16, b_qk, qk16);
    hipLaunchKernelGGL(k_attn, dim3(BATCH * NH * S_LEN), dim3(256), 0, stream, qk16, val16, cnt, idx, ao16);
    hipLaunchKernelGGL((k_gemm16<false, 32, DIM, float>), dim3(BATCH * S_LEN / 64, DIM / 64), dim3(256), 0, stream,
                       ao16, wpt, b_proj, out);
}

// Round 25
// 285.814 us; speedup vs baseline: 1.7062x; 1.0814x over previous
//
#include <hip/hip_runtime.h>
#include <hip/hip_bf16.h>
#include <hip/hip_fp16.h>

#define S_LEN 2048
#define BATCH 2
#define DIM 128
#define NH 8
#define HD 1024
#define QL 5
#define KKTOT 640   // DIM*QL
#define OCH 2048
#define MAXNNZ 384

typedef _Float16 hv2 __attribute__((ext_vector_type(2)));
typedef _Float16 f16x8 __attribute__((ext_vector_type(8)));
typedef float f32x4 __attribute__((ext_vector_type(4)));

#if defined(__has_builtin)
#  if __has_builtin(__builtin_amdgcn_fdot2)
#    define USE_FDOT2 1
#  endif
#endif
#ifndef USE_FDOT2
#  define USE_FDOT2 0
#endif

__device__ __forceinline__ hv2 u2h(unsigned u) {
    union { unsigned u; hv2 h; } c; c.u = u; return c.h;
}
__device__ __forceinline__ float dot2acc(unsigned a, unsigned b, float acc) {
#if USE_FDOT2
    return __builtin_amdgcn_fdot2(u2h(a), u2h(b), acc, false);
#else
    hv2 ha = u2h(a), hb = u2h(b);
    return acc + (float)ha[0] * (float)hb[0] + (float)ha[1] * (float)hb[1];
#endif
}

// ---------------- fused preprocessing: x->fp16, w_qk->bt16 (t-major), w_v/w_proj transpose
__global__ void k_prep(const float* __restrict__ x, const float* __restrict__ w_qk,
                       const float* __restrict__ wv, const float* __restrict__ wp,
                       _Float16* __restrict__ x16, _Float16* __restrict__ bt,
                       _Float16* __restrict__ wvt, _Float16* __restrict__ wpt) {
    int i = blockIdx.x * 256 + threadIdx.x;
    if (i < OCH * KKTOT) {                       // bt16[o][k], k = t*128+i
        int o = i / KKTOT, k = i % KKTOT;
        int t = k >> 7, ii = k & 127;
        bt[i] = (_Float16)w_qk[(size_t)o * KKTOT + ii * QL + t];
        return;
    }
    i -= OCH * KKTOT;
    if (i < BATCH * S_LEN * DIM) {               // x16
        x16[i] = (_Float16)x[i];
        return;
    }
    i -= BATCH * S_LEN * DIM;
    if (i < HD * DIM) {                          // wvt[c][k] = wv[k][c]
        int c = i >> 7, k = i & 127;
        wvt[i] = (_Float16)wv[(size_t)k * HD + c];
        return;
    }
    i -= HD * DIM;
    if (i < DIM * HD) {                          // wpt[c][k] = wp[k][c]
        int c = i >> 10, k = i & 1023;
        wpt[i] = (_Float16)wp[(size_t)k * DIM + c];
    }
}

// ---------------- compact mask rows to CSR (u16 indices)
__global__ void k_mask_csr(const float* __restrict__ mask, unsigned* __restrict__ cnt,
                           unsigned short* __restrict__ idx) {
    __shared__ unsigned s_base;
    __shared__ unsigned s_wcnt[4];
    int r = blockIdx.x;
    int tid = threadIdx.x;
    int lane = tid & 63;
    int w = tid >> 6;
    if (tid == 0) s_base = 0;
    __syncthreads();
    for (int c0 = 0; c0 < S_LEN; c0 += 256) {
        int c = c0 + tid;
        bool act = mask[(size_t)r * S_LEN + c] > 0.5f;
        unsigned long long bal = __ballot(act);
        if (lane == 0) s_wcnt[w] = (unsigned)__popcll(bal);
        __syncthreads();
        unsigned off = s_base;
        for (int i = 0; i < w; i++) off += s_wcnt[i];
        off += (unsigned)__popcll(bal & ((1ull << lane) - 1ull));
        if (act && off < MAXNNZ) idx[r * MAXNNZ + off] = (unsigned short)c;
        __syncthreads();
        if (tid == 0) s_base += s_wcnt[0] + s_wcnt[1] + s_wcnt[2] + s_wcnt[3];
        __syncthreads();
    }
    if (tid == 0) cnt[r] = (s_base < MAXNNZ) ? s_base : MAXNNZ;
}

// ---------------- register-MFMA GEMM: C[4096][NN] = A(x16/im2col) x Bt^T + bias
template<bool CONV, int KSTEPS, int NN, typename OutT>
__global__ void __launch_bounds__(256) k_gemm16(const _Float16* __restrict__ A,
                                                const _Float16* __restrict__ Bt,
                                                const float* __restrict__ bias,
                                                OutT* __restrict__ C) {
    const int K = KSTEPS * 32;
    int tid = threadIdx.x;
    int lane = tid & 63, wave = tid >> 6;
    int wr = wave >> 1, wc = wave & 1;
    int l15 = lane & 15, lk = lane >> 4;
    int rbase = blockIdx.x * 64;            // global row base
    int batch = rbase >> 11;
    int s0 = rbase & 2047;                  // batch-local row base
    f32x4 acc[2][2] = {};
    for (int ks = 0; ks < KSTEPS; ks++) {
        int t = CONV ? (ks >> 2) : 0;
        int i0 = CONV ? ((ks & 3) * 32) : (ks * 32);
        f16x8 afr[2], bfr[2];
#pragma unroll
        for (int a = 0; a < 2; a++) {
            int srow = s0 + wr * 32 + a * 16 + l15;
            int sx = CONV ? (srow - (QL - 1) + t) : srow;
            int sclamp = sx < 0 ? 0 : sx;
            f16x8 av = *reinterpret_cast<const f16x8*>(
                A + ((size_t)(batch * S_LEN + sclamp)) * (CONV ? DIM : (K)) + i0 + lk * 8);
            if (CONV && sx < 0) av = f16x8{0, 0, 0, 0, 0, 0, 0, 0};
            afr[a] = av;
        }
#pragma unroll
        for (int bb = 0; bb < 2; bb++) {
            int col = blockIdx.y * 64 + wc * 32 + bb * 16 + l15;
            bfr[bb] = *reinterpret_cast<const f16x8*>(Bt + (size_t)col * K + ks * 32 + lk * 8);
        }
#pragma unroll
        for (int a = 0; a < 2; a++)
#pragma unroll
            for (int bb = 0; bb < 2; bb++)
                acc[a][bb] = __builtin_amdgcn_mfma_f32_16x16x32_f16(afr[a], bfr[bb], acc[a][bb], 0, 0, 0);
    }
#pragma unroll
    for (int a = 0; a < 2; a++)
#pragma unroll
        for (int bb = 0; bb < 2; bb++) {
            int col = blockIdx.y * 64 + wc * 32 + bb * 16 + l15;
            float bs = bias[col];
#pragma unroll
            for (int j = 0; j < 4; j++) {
                int row = rbase + wr * 32 + a * 16 + lk * 4 + j;   // C/D: row=(lane>>4)*4+j, col=lane&15
                C[(size_t)row * NN + col] = (OutT)(acc[a][bb][j] + bs);
            }
        }
}

// ---------------- sparse attention + entmax15 (Newton-8 on wave 0), fp16 out
// Phase 1: 2-col unroll (MLP); PV: dual-slot unroll; u16 CSR.
__global__ void __launch_bounds__(256) k_attn(const _Float16* __restrict__ qk16,
                                              const _Float16* __restrict__ val16,
                                              const unsigned* __restrict__ cnt,
                                              const unsigned short* __restrict__ idxbuf,
                                              _Float16* __restrict__ attout) {
    __shared__ float ssc[MAXNNZ];
    __shared__ unsigned short sidx[MAXNNZ];
    __shared__ float pvs[16][136];
    int l = blockIdx.x;
    int bid = (l & 7) * 4096 + (l >> 3);   // XCD swizzle (32768 = 8 * 4096, bijective)
    int r = bid & (S_LEN - 1);
    int h = (bid >> 11) & (NH - 1);
    int b = bid >> 14;
    int tid = threadIdx.x;
    int lane = tid & 63;
    int wave = tid >> 6;
    int n = (int)cnt[r];
    const float scale = 0.08838834764831843f;  // 1/sqrt(128)

    for (int j = tid; j < n; j += 256) sidx[j] = idxbuf[r * MAXNNZ + j];
    __syncthreads();

    // ---- phase 1: scores; fp16 q in registers, 2 columns per iteration (MLP)
    {
        int grp = tid >> 2;          // 0..63
        int ll  = tid & 3;           // lane within group
        const uint4* q16 = reinterpret_cast<const uint4*>(
                               qk16 + ((size_t)(b * S_LEN + r)) * OCH + h * 128);
        uint4 qreg[4];
#pragma unroll
        for (int i = 0; i < 4; i++) qreg[i] = q16[i * 4 + ll];
        const _Float16* kbase = qk16 + (size_t)b * S_LEN * OCH + HD + h * 128;
        for (int j0 = grp; j0 < n; j0 += 128) {
            int j1 = j0 + 64;
            bool has1 = j1 < n;
            const uint4* kp0 = reinterpret_cast<const uint4*>(kbase + (size_t)sidx[j0] * OCH);
            const uint4* kp1 = has1 ? reinterpret_cast<const uint4*>(kbase + (size_t)sidx[j1] * OCH) : kp0;
            float p0 = 0.f, p1 = 0.f;
#pragma unroll
            for (int i = 0; i < 4; i++) {
                uint4 kv0 = kp0[i * 4 + ll];
                uint4 kv1 = kp1[i * 4 + ll];
                const unsigned* ka0 = reinterpret_cast<const unsigned*>(&kv0);
                const unsigned* ka1 = reinterpret_cast<const unsigned*>(&kv1);
                const unsigned* qa = reinterpret_cast<const unsigned*>(&qreg[i]);
#pragma unroll
                for (int c = 0; c < 4; c++) {
                    p0 = dot2acc(qa[c], ka0[c], p0);
                    p1 = dot2acc(qa[c], ka1[c], p1);
                }
            }
            p0 += __shfl_xor(p0, 1, 64);
            p0 += __shfl_xor(p0, 2, 64);
            p1 += __shfl_xor(p1, 1, 64);
            p1 += __shfl_xor(p1, 2, 64);
            if (ll == 0) {
                ssc[j0] = p0 * scale;
                if (has1) ssc[j1] = p1 * scale;
            }
        }
    }
    __syncthreads();

    // ---- phase 2: entmax tau on wave 0 — fused max + Newton-from-below (8 it)
    if (wave == 0) {
        float xl[6];
        float mx = -3.0e38f;
#pragma unroll
        for (int l2 = 0; l2 < 6; l2++) {
            int j = lane + 64 * l2;
            xl[l2] = (j < n) ? ssc[j] * 0.5f : -3.0e38f;
            mx = fmaxf(mx, xl[l2]);
        }
#pragma unroll
        for (int off = 32; off >= 1; off >>= 1) mx = fmaxf(mx, __shfl_xor(mx, off, 64));
        float tau = mx - 1.f;
        for (int it = 0; it < 8; it++) {
            float s1 = 0.f, s2 = 0.f;
#pragma unroll
            for (int l2 = 0; l2 < 6; l2++) {
                float d = fmaxf(xl[l2] - tau, 0.f);
                s1 += d;
                s2 += d * d;
            }
#pragma unroll
            for (int off = 32; off >= 1; off >>= 1) {
                s1 += __shfl_xor(s1, off, 64);
                s2 += __shfl_xor(s2, off, 64);
            }
            tau += (s2 - 1.f) / (2.f * s1);
        }
#pragma unroll
        for (int l2 = 0; l2 < 6; l2++) {
            int j = lane + 64 * l2;
            if (j < n) {
                float d = fmaxf(xl[l2] - tau, 0.f);
                ssc[j] = d * d;
            }
        }
    }
    __syncthreads();

    // ---- phase 3: PV, fp16 V — 16 slots x 16 dim-groups, dual-slot unroll
    {
        int slot = tid >> 4;         // 0..15
        int dg   = tid & 15;         // 0..15, dims dg*8..dg*8+7
        const uint4* vbase = reinterpret_cast<const uint4*>(
                                 val16 + (size_t)b * S_LEN * HD + h * 128) + dg;
        float accA[8], accB[8];
#pragma unroll
        for (int k = 0; k < 8; k++) { accA[k] = 0.f; accB[k] = 0.f; }
        int j = slot;
        for (; j + 16 < n; j += 32) {
            float wA = ssc[j];
            float wB = ssc[j + 16];
            uint4 vvA = vbase[(size_t)sidx[j] << 7];
            uint4 vvB = vbase[(size_t)sidx[j + 16] << 7];
            const __half2* vaA = reinterpret_cast<const __half2*>(&vvA);
            const __half2* vaB = reinterpret_cast<const __half2*>(&vvB);
#pragma unroll
            for (int k = 0; k < 4; k++) {
                float2 fA = __half22float2(vaA[k]);
                float2 fB = __half22float2(vaB[k]);
                accA[2 * k]     += wA * fA.x;
                accA[2 * k + 1] += wA * fA.y;
                accB[2 * k]     += wB * fB.x;
                accB[2 * k + 1] += wB * fB.y;
            }
        }
        if (j < n) {
            float wA = ssc[j];
            uint4 vv = vbase[(size_t)sidx[j] << 7];
            const __half2* va = reinterpret_cast<const __half2*>(&vv);
#pragma unroll
            for (int k = 0; k < 4; k++) {
                float2 f = __half22float2(va[k]);
                accA[2 * k]     += wA * f.x;
                accA[2 * k + 1] += wA * f.y;
            }
        }
        float4 v0 = {accA[0] + accB[0], accA[1] + accB[1], accA[2] + accB[2], accA[3] + accB[3]};
        float4 v1 = {accA[4] + accB[4], accA[5] + accB[5], accA[6] + accB[6], accA[7] + accB[7]};
        *reinterpret_cast<float4*>(&pvs[slot][dg * 8]) = v0;
        *reinterpret_cast<float4*>(&pvs[slot][dg * 8 + 4]) = v1;
    }
    __syncthreads();
    if (tid < 128) {
        float a = 0.f;
#pragma unroll
        for (int s = 0; s < 16; s++) a += pvs[s][tid];
        attout[((size_t)(b * S_LEN + r)) * HD + h * 128 + tid] = (_Float16)a;
    }
}

extern "C" void kernel_launch(void* const* d_in, const int* in_sizes, int n_in,
                              void* d_out, int out_size, void* d_ws, size_t ws_size,
                              hipStream_t stream) {
    const float* x      = (const float*)d_in[0];
    const float* mask   = (const float*)d_in[1];
    const float* w_qk   = (const float*)d_in[2];
    const float* b_qk   = (const float*)d_in[3];
    const float* w_v    = (const float*)d_in[4];
    const float* b_v    = (const float*)d_in[5];
    const float* w_proj = (const float*)d_in[6];
    const float* b_proj = (const float*)d_in[7];
    float* out = (float*)d_out;     // reference output dtype is FLOAT32

    char* ws = (char*)d_ws;
    _Float16*       x16   = (_Float16*)(ws + 0);         //  1,048,576 B
    _Float16*       qk16  = (_Float16*)(ws + 1048576);   // 16,777,216 B
    _Float16*       val16 = (_Float16*)(ws + 17825792);  //  8,388,608 B
    _Float16*       bt16  = (_Float16*)(ws + 26214400);  //  2,621,440 B  [2048][640]
    _Float16*       wvt   = (_Float16*)(ws + 28835840);  //    262,144 B  [1024][128]
    _Float16*       wpt   = (_Float16*)(ws + 29097984);  //    262,144 B  [128][1024]
    unsigned*       cnt   = (unsigned*)(ws + 29360128);  //      8,192 B
    unsigned short* idx   = (unsigned short*)(ws + 29368320);  // 1,572,864 B (u16)
    _Float16*       ao16  = (_Float16*)(ws + 32514048);  //  8,388,608 B -> end 40,902,656

    hipLaunchKernelGGL(k_prep, dim3(8192), dim3(256), 0, stream,
                       x, w_qk, w_v, w_proj, x16, bt16, wvt, wpt);
    hipLaunchKernelGGL(k_mask_csr, dim3(S_LEN), dim3(256), 0, stream, mask, cnt, idx);
    hipLaunchKernelGGL((k_gemm16<false, 4, HD, _Float16>), dim3(BATCH * S_LEN / 64, HD / 64), dim3(256), 0, stream,
                       x16, wvt, b_v, val16);
    hipLaunchKernelGGL((k_gemm16<true, 20, OCH, _Float16>), dim3(BATCH * S_LEN / 64, OCH / 64), dim3(256), 0, stream,
                       x16, bt16, b_qk, qk16);
    hipLaunchKernelGGL(k_attn, dim3(BATCH * NH * S_LEN), dim3(256), 0, stream, qk16, val16, cnt, idx, ao16);
    hipLaunchKernelGGL((k_gemm16<false, 32, DIM, float>), dim3(BATCH * S_LEN / 64, DIM / 64), dim3(256), 0, stream,
                       ao16, wpt, b_proj, out);
}

// Round 26
// 278.112 us; speedup vs baseline: 1.7534x; 1.0277x over previous
//
#include <hip/hip_runtime.h>
#include <hip/hip_bf16.h>
#include <hip/hip_fp16.h>

#define S_LEN 2048
#define BATCH 2
#define DIM 128
#define NH 8
#define HD 1024
#define QL 5
#define KKTOT 640   // DIM*QL
#define OCH 2048
#define MAXNNZ 384

typedef _Float16 hv2 __attribute__((ext_vector_type(2)));
typedef _Float16 f16x8 __attribute__((ext_vector_type(8)));
typedef float f32x4 __attribute__((ext_vector_type(4)));

#if defined(__has_builtin)
#  if __has_builtin(__builtin_amdgcn_fdot2)
#    define USE_FDOT2 1
#  endif
#endif
#ifndef USE_FDOT2
#  define USE_FDOT2 0
#endif

__device__ __forceinline__ hv2 u2h(unsigned u) {
    union { unsigned u; hv2 h; } c; c.u = u; return c.h;
}
__device__ __forceinline__ float dot2acc(unsigned a, unsigned b, float acc) {
#if USE_FDOT2
    return __builtin_amdgcn_fdot2(u2h(a), u2h(b), acc, false);
#else
    hv2 ha = u2h(a), hb = u2h(b);
    return acc + (float)ha[0] * (float)hb[0] + (float)ha[1] * (float)hb[1];
#endif
}

// ---------------- fused preprocessing: x->fp16, w_qk->bt16 (t-major), w_v/w_proj transpose
__global__ void k_prep(const float* __restrict__ x, const float* __restrict__ w_qk,
                       const float* __restrict__ wv, const float* __restrict__ wp,
                       _Float16* __restrict__ x16, _Float16* __restrict__ bt,
                       _Float16* __restrict__ wvt, _Float16* __restrict__ wpt) {
    int i = blockIdx.x * 256 + threadIdx.x;
    if (i < OCH * KKTOT) {                       // bt16[o][k], k = t*128+i
        int o = i / KKTOT, k = i % KKTOT;
        int t = k >> 7, ii = k & 127;
        bt[i] = (_Float16)w_qk[(size_t)o * KKTOT + ii * QL + t];
        return;
    }
    i -= OCH * KKTOT;
    if (i < BATCH * S_LEN * DIM) {               // x16
        x16[i] = (_Float16)x[i];
        return;
    }
    i -= BATCH * S_LEN * DIM;
    if (i < HD * DIM) {                          // wvt[c][k] = wv[k][c]
        int c = i >> 7, k = i & 127;
        wvt[i] = (_Float16)wv[(size_t)k * HD + c];
        return;
    }
    i -= HD * DIM;
    if (i < DIM * HD) {                          // wpt[c][k] = wp[k][c]
        int c = i >> 10, k = i & 1023;
        wpt[i] = (_Float16)wp[(size_t)k * DIM + c];
    }
}

// ---------------- compact mask rows to CSR (u16 indices)
__global__ void k_mask_csr(const float* __restrict__ mask, unsigned* __restrict__ cnt,
                           unsigned short* __restrict__ idx) {
    __shared__ unsigned s_base;
    __shared__ unsigned s_wcnt[4];
    int r = blockIdx.x;
    int tid = threadIdx.x;
    int lane = tid & 63;
    int w = tid >> 6;
    if (tid == 0) s_base = 0;
    __syncthreads();
    for (int c0 = 0; c0 < S_LEN; c0 += 256) {
        int c = c0 + tid;
        bool act = mask[(size_t)r * S_LEN + c] > 0.5f;
        unsigned long long bal = __ballot(act);
        if (lane == 0) s_wcnt[w] = (unsigned)__popcll(bal);
        __syncthreads();
        unsigned off = s_base;
        for (int i = 0; i < w; i++) off += s_wcnt[i];
        off += (unsigned)__popcll(bal & ((1ull << lane) - 1ull));
        if (act && off < MAXNNZ) idx[r * MAXNNZ + off] = (unsigned short)c;
        __syncthreads();
        if (tid == 0) s_base += s_wcnt[0] + s_wcnt[1] + s_wcnt[2] + s_wcnt[3];
        __syncthreads();
    }
    if (tid == 0) cnt[r] = (s_base < MAXNNZ) ? s_base : MAXNNZ;
}

// ---------------- register-MFMA GEMM: C[4096][NN] = A(x16/im2col) x Bt^T + bias
template<bool CONV, int KSTEPS, int NN, typename OutT>
__global__ void __launch_bounds__(256) k_gemm16(const _Float16* __restrict__ A,
                                                const _Float16* __restrict__ Bt,
                                                const float* __restrict__ bias,
                                                OutT* __restrict__ C) {
    const int K = KSTEPS * 32;
    int tid = threadIdx.x;
    int lane = tid & 63, wave = tid >> 6;
    int wr = wave >> 1, wc = wave & 1;
    int l15 = lane & 15, lk = lane >> 4;
    int rbase = blockIdx.x * 64;            // global row base
    int batch = rbase >> 11;
    int s0 = rbase & 2047;                  // batch-local row base
    f32x4 acc[2][2] = {};
    for (int ks = 0; ks < KSTEPS; ks++) {
        int t = CONV ? (ks >> 2) : 0;
        int i0 = CONV ? ((ks & 3) * 32) : (ks * 32);
        f16x8 afr[2], bfr[2];
#pragma unroll
        for (int a = 0; a < 2; a++) {
            int srow = s0 + wr * 32 + a * 16 + l15;
            int sx = CONV ? (srow - (QL - 1) + t) : srow;
            int sclamp = sx < 0 ? 0 : sx;
            f16x8 av = *reinterpret_cast<const f16x8*>(
                A + ((size_t)(batch * S_LEN + sclamp)) * (CONV ? DIM : (K)) + i0 + lk * 8);
            if (CONV && sx < 0) av = f16x8{0, 0, 0, 0, 0, 0, 0, 0};
            afr[a] = av;
        }
#pragma unroll
        for (int bb = 0; bb < 2; bb++) {
            int col = blockIdx.y * 64 + wc * 32 + bb * 16 + l15;
            bfr[bb] = *reinterpret_cast<const f16x8*>(Bt + (size_t)col * K + ks * 32 + lk * 8);
        }
#pragma unroll
        for (int a = 0; a < 2; a++)
#pragma unroll
            for (int bb = 0; bb < 2; bb++)
                acc[a][bb] = __builtin_amdgcn_mfma_f32_16x16x32_f16(afr[a], bfr[bb], acc[a][bb], 0, 0, 0);
    }
#pragma unroll
    for (int a = 0; a < 2; a++)
#pragma unroll
        for (int bb = 0; bb < 2; bb++) {
            int col = blockIdx.y * 64 + wc * 32 + bb * 16 + l15;
            float bs = bias[col];
#pragma unroll
            for (int j = 0; j < 4; j++) {
                int row = rbase + wr * 32 + a * 16 + lk * 4 + j;   // C/D: row=(lane>>4)*4+j, col=lane&15
                C[(size_t)row * NN + col] = (OutT)(acc[a][bb][j] + bs);
            }
        }
}

// ---------------- sparse attention + entmax15 (Newton-8 on wave 0), fp16 out
// Phase 1: 2-col unroll; PV: packed v_pk_fma_f16 accumulation, dual-slot.
__global__ void __launch_bounds__(256) k_attn(const _Float16* __restrict__ qk16,
                                              const _Float16* __restrict__ val16,
                                              const unsigned* __restrict__ cnt,
                                              const unsigned short* __restrict__ idxbuf,
                                              _Float16* __restrict__ attout) {
    __shared__ float ssc[MAXNNZ];
    __shared__ unsigned short sidx[MAXNNZ];
    __shared__ float pvs[16][136];
    int l = blockIdx.x;
    int bid = (l & 7) * 4096 + (l >> 3);   // XCD swizzle (32768 = 8 * 4096, bijective)
    int r = bid & (S_LEN - 1);
    int h = (bid >> 11) & (NH - 1);
    int b = bid >> 14;
    int tid = threadIdx.x;
    int lane = tid & 63;
    int wave = tid >> 6;
    int n = (int)cnt[r];
    const float scale = 0.08838834764831843f;  // 1/sqrt(128)

    for (int j = tid; j < n; j += 256) sidx[j] = idxbuf[r * MAXNNZ + j];
    __syncthreads();

    // ---- phase 1: scores; fp16 q in registers, 2 columns per iteration (MLP)
    {
        int grp = tid >> 2;          // 0..63
        int ll  = tid & 3;           // lane within group
        const uint4* q16 = reinterpret_cast<const uint4*>(
                               qk16 + ((size_t)(b * S_LEN + r)) * OCH + h * 128);
        uint4 qreg[4];
#pragma unroll
        for (int i = 0; i < 4; i++) qreg[i] = q16[i * 4 + ll];
        const _Float16* kbase = qk16 + (size_t)b * S_LEN * OCH + HD + h * 128;
        for (int j0 = grp; j0 < n; j0 += 128) {
            int j1 = j0 + 64;
            bool has1 = j1 < n;
            const uint4* kp0 = reinterpret_cast<const uint4*>(kbase + (size_t)sidx[j0] * OCH);
            const uint4* kp1 = has1 ? reinterpret_cast<const uint4*>(kbase + (size_t)sidx[j1] * OCH) : kp0;
            float p0 = 0.f, p1 = 0.f;
#pragma unroll
            for (int i = 0; i < 4; i++) {
                uint4 kv0 = kp0[i * 4 + ll];
                uint4 kv1 = kp1[i * 4 + ll];
                const unsigned* ka0 = reinterpret_cast<const unsigned*>(&kv0);
                const unsigned* ka1 = reinterpret_cast<const unsigned*>(&kv1);
                const unsigned* qa = reinterpret_cast<const unsigned*>(&qreg[i]);
#pragma unroll
                for (int c = 0; c < 4; c++) {
                    p0 = dot2acc(qa[c], ka0[c], p0);
                    p1 = dot2acc(qa[c], ka1[c], p1);
                }
            }
            p0 += __shfl_xor(p0, 1, 64);
            p0 += __shfl_xor(p0, 2, 64);
            p1 += __shfl_xor(p1, 1, 64);
            p1 += __shfl_xor(p1, 2, 64);
            if (ll == 0) {
                ssc[j0] = p0 * scale;
                if (has1) ssc[j1] = p1 * scale;
            }
        }
    }
    __syncthreads();

    // ---- phase 2: entmax tau on wave 0 — fused max + Newton-from-below (8 it)
    if (wave == 0) {
        float xl[6];
        float mx = -3.0e38f;
#pragma unroll
        for (int l2 = 0; l2 < 6; l2++) {
            int j = lane + 64 * l2;
            xl[l2] = (j < n) ? ssc[j] * 0.5f : -3.0e38f;
            mx = fmaxf(mx, xl[l2]);
        }
#pragma unroll
        for (int off = 32; off >= 1; off >>= 1) mx = fmaxf(mx, __shfl_xor(mx, off, 64));
        float tau = mx - 1.f;
        for (int it = 0; it < 8; it++) {
            float s1 = 0.f, s2 = 0.f;
#pragma unroll
            for (int l2 = 0; l2 < 6; l2++) {
                float d = fmaxf(xl[l2] - tau, 0.f);
                s1 += d;
                s2 += d * d;
            }
#pragma unroll
            for (int off = 32; off >= 1; off >>= 1) {
                s1 += __shfl_xor(s1, off, 64);
                s2 += __shfl_xor(s2, off, 64);
            }
            tau += (s2 - 1.f) / (2.f * s1);
        }
#pragma unroll
        for (int l2 = 0; l2 < 6; l2++) {
            int j = lane + 64 * l2;
            if (j < n) {
                float d = fmaxf(xl[l2] - tau, 0.f);
                ssc[j] = d * d;
            }
        }
    }
    __syncthreads();

    // ---- phase 3: PV in packed fp16 (v_pk_fma_f16), dual-slot unroll
    {
        int slot = tid >> 4;         // 0..15
        int dg   = tid & 15;         // dims dg*8..dg*8+7
        const uint4* vbase = reinterpret_cast<const uint4*>(
                                 val16 + (size_t)b * S_LEN * HD + h * 128) + dg;
        hv2 accA[4] = {};
        hv2 accB[4] = {};
        int j = slot;
        for (; j + 16 < n; j += 32) {
            _Float16 wA = (_Float16)ssc[j];
            _Float16 wB = (_Float16)ssc[j + 16];
            hv2 wA2 = {wA, wA};
            hv2 wB2 = {wB, wB};
            uint4 vvA = vbase[(size_t)sidx[j] << 7];
            uint4 vvB = vbase[(size_t)sidx[j + 16] << 7];
            const hv2* vaA = reinterpret_cast<const hv2*>(&vvA);
            const hv2* vaB = reinterpret_cast<const hv2*>(&vvB);
#pragma unroll
            for (int k = 0; k < 4; k++) {
                accA[k] += wA2 * vaA[k];    // v_pk_fma_f16
                accB[k] += wB2 * vaB[k];
            }
        }
        if (j < n) {
            _Float16 wA = (_Float16)ssc[j];
            hv2 wA2 = {wA, wA};
            uint4 vv = vbase[(size_t)sidx[j] << 7];
            const hv2* va = reinterpret_cast<const hv2*>(&vv);
#pragma unroll
            for (int k = 0; k < 4; k++) accA[k] += wA2 * va[k];
        }
        float4 v0, v1;
        v0.x = (float)accA[0][0] + (float)accB[0][0];
        v0.y = (float)accA[0][1] + (float)accB[0][1];
        v0.z = (float)accA[1][0] + (float)accB[1][0];
        v0.w = (float)accA[1][1] + (float)accB[1][1];
        v1.x = (float)accA[2][0] + (float)accB[2][0];
        v1.y = (float)accA[2][1] + (float)accB[2][1];
        v1.z = (float)accA[3][0] + (float)accB[3][0];
        v1.w = (float)accA[3][1] + (float)accB[3][1];
        *reinterpret_cast<float4*>(&pvs[slot][dg * 8]) = v0;
        *reinterpret_cast<float4*>(&pvs[slot][dg * 8 + 4]) = v1;
    }
    __syncthreads();
    if (tid < 128) {
        float a = 0.f;
#pragma unroll
        for (int s = 0; s < 16; s++) a += pvs[s][tid];
        attout[((size_t)(b * S_LEN + r)) * HD + h * 128 + tid] = (_Float16)a;
    }
}

extern "C" void kernel_launch(void* const* d_in, const int* in_sizes, int n_in,
                              void* d_out, int out_size, void* d_ws, size_t ws_size,
                              hipStream_t stream) {
    const float* x      = (const float*)d_in[0];
    const float* mask   = (const float*)d_in[1];
    const float* w_qk   = (const float*)d_in[2];
    const float* b_qk   = (const float*)d_in[3];
    const float* w_v    = (const float*)d_in[4];
    const float* b_v    = (const float*)d_in[5];
    const float* w_proj = (const float*)d_in[6];
    const float* b_proj = (const float*)d_in[7];
    float* out = (float*)d_out;     // reference output dtype is FLOAT32

    char* ws = (char*)d_ws;
    _Float16*       x16   = (_Float16*)(ws + 0);         //  1,048,576 B
    _Float16*       qk16  = (_Float16*)(ws + 1048576);   // 16,777,216 B
    _Float16*       val16 = (_Float16*)(ws + 17825792);  //  8,388,608 B
    _Float16*       bt16  = (_Float16*)(ws + 26214400);  //  2,621,440 B  [2048][640]
    _Float16*       wvt   = (_Float16*)(ws + 28835840);  //    262,144 B  [1024][128]
    _Float16*       wpt   = (_Float16*)(ws + 29097984);  //    262,144 B  [128][1024]
    unsigned*       cnt   = (unsigned*)(ws + 29360128);  //      8,192 B
    unsigned short* idx   = (unsigned short*)(ws + 29368320);  // 1,572,864 B (u16)
    _Float16*       ao16  = (_Float16*)(ws + 32514048);  //  8,388,608 B -> end 40,902,656

    hipLaunchKernelGGL(k_prep, dim3(8192), dim3(256), 0, stream,
                       x, w_qk, w_v, w_proj, x16, bt16, wvt, wpt);
    hipLaunchKernelGGL(k_mask_csr, dim3(S_LEN), dim3(256), 0, stream, mask, cnt, idx);
    hipLaunchKernelGGL((k_gemm16<false, 4, HD, _Float16>), dim3(BATCH * S_LEN / 64, HD / 64), dim3(256), 0, stream,
                       x16, wvt, b_v, val16);
    hipLaunchKernelGGL((k_gemm16<true, 20, OCH, _Float16>), dim3(BATCH * S_LEN / 64, OCH / 64), dim3(256), 0, stream,
                       x16, bt16, b_qk, qk16);
    hipLaunchKernelGGL(k_attn, dim3(BATCH * NH * S_LEN), dim3(256), 0, stream, qk16, val16, cnt, idx, ao16);
    hipLaunchKernelGGL((k_gemm16<false, 32, DIM, float>), dim3(BATCH * S_LEN / 64, DIM / 64), dim3(256), 0, stream,
                       ao16, wpt, b_proj, out);
}